// Round 7
// baseline (566.216 us; speedup 1.0000x reference)
//
#include <hip/hip_runtime.h>
#include <hip/hip_fp16.h>

// ---------------------------------------------------------------------------
// LinkPredictionGNN: 2x GCNConv (self-loops, sym-norm) + pair MLP head.
//   CSR build: bucket hist -> scan -> multisplit -> per-bucket LDS sort
//   g1 = fp16( dinv * (x @ W1) )                        [k_gemm_mfma]
//   h1 = relu(dinv * (gather-sum g1 + g1) + b1)         [k_agg_s, sliced]
//   g2 = fp16( dinv * (h1 @ W2) )                       [k_gemm_mfma]
//   h2 = relu(dinv * (gather-sum g2 + g2) + b2)         [k_agg_s]
//   A = fp16(h2 @ Wh1_top), B = fp16(h2 @ Wh1_bot)      [k_gemm_mfma x2]
//   out[p] = relu(A[p0]+B[p1]+bh1) . Wh2 + bh2          [pairs_h]
//
// R1/R4 lesson: random 4B global writes/atomics carry ~10x line-writeback
// amplification regardless of block placement (XCC pinning regressed).
// R5: CSR build = 2-level bucket sort (multisplit + per-bucket LDS sort),
//     zero global random atomics. CSR cost now negligible.
// R6: agg was L2-capacity bound (FETCH 170MB vs 12.8MB table; 4MB/XCD L2
//     ~58% hit). Column-sliced gather: 4 slices x 32 cols; blockIdx%4 =
//     slice -> round-robin XCD dispatch keeps one 3.2MB slice per XCD L2.
//     Per edge-slice load = 64B = one full line (no over-fetch); colarr
//     re-read 4x with nt loads (cheap, 25MB).
// R2: fp16 message/A/B tables (absmax 4.9e-4 < 1.5e-3 threshold).
// R3: double-bf16-split MFMA GEMM (Ah.Bh+Al.Bh+Ah.Bl), no LDS/barriers.
// ---------------------------------------------------------------------------

#define BSH 9                 // log2 nodes per bucket
#define BSZ (1 << BSH)        // 512 nodes per bucket
#define MSB 4096              // edges per multisplit batch/block

typedef __attribute__((ext_vector_type(8))) short bf16x8;
typedef __attribute__((ext_vector_type(4))) float f32x4;

__global__ __launch_bounds__(256) void k_zero_i32(int* __restrict__ p, int n) {
  int i = blockIdx.x * 256 + threadIdx.x;
  if (i < n) p[i] = 0;
}

// per-block LDS histogram of dst into buckets of BSZ nodes
__global__ __launch_bounds__(256) void k_bucket_hist(const int* __restrict__ dst,
                                                     int* __restrict__ gcnt,
                                                     int e, int kb) {
  __shared__ int h[128];
  int tid = threadIdx.x;
  if (tid < kb) h[tid] = 0;
  __syncthreads();
  int stride = gridDim.x * 256;
  for (int i = blockIdx.x * 256 + tid; i < e; i += stride) {
    int d = __builtin_nontemporal_load(&dst[i]);
    atomicAdd(&h[d >> BSH], 1);
  }
  __syncthreads();
  if (tid < kb) atomicAdd(&gcnt[tid], h[tid]);
}

// 1 block, 128 threads: exclusive scan of bucket counts -> gbase, gcur
__global__ __launch_bounds__(128) void k_bucket_scan(const int* __restrict__ gcnt,
                                                     int* __restrict__ gbase,
                                                     int* __restrict__ gcur,
                                                     int kb) {
  __shared__ int ws[2];
  int t = threadIdx.x;
  int lane = t & 63, w = t >> 6;
  int v = (t < kb) ? gcnt[t] : 0;
  int orig = v;
#pragma unroll
  for (int o = 1; o < 64; o <<= 1) {
    int u = __shfl_up(v, o, 64);
    if (lane >= o) v += u;
  }
  if (lane == 63) ws[w] = v;
  __syncthreads();
  int ex = ((w == 1) ? ws[0] : 0) + v - orig;
  if (t < kb) { gbase[t] = ex; gcur[t] = ex; }
  if (t == kb - 1) gbase[kb] = ex + orig;
}

// multisplit: one 4096-edge batch per block; per-edge intra-bucket rank from
// LDS histogram; one global atomic per bucket per batch reserves a contiguous
// segment; packed edge = (d_local << 16) | src   [valid: src < 65536]
__global__ __launch_bounds__(256) void k_multisplit(const int* __restrict__ src,
                                                    const int* __restrict__ dst,
                                                    int* __restrict__ gcur,
                                                    int* __restrict__ tmp,
                                                    int e, int kb) {
  __shared__ int h[128], base[128];
  int tid = threadIdx.x;
  if (tid < kb) h[tid] = 0;
  __syncthreads();
  int i0 = blockIdx.x * MSB + tid;
  int d[16], rk[16];
#pragma unroll
  for (int u = 0; u < 16; ++u) {
    int i = i0 + u * 256;
    if (i < e) {
      d[u] = __builtin_nontemporal_load(&dst[i]);
      rk[u] = atomicAdd(&h[d[u] >> BSH], 1);
    }
  }
  __syncthreads();
  if (tid < kb && h[tid] > 0) base[tid] = atomicAdd(&gcur[tid], h[tid]);
  __syncthreads();
#pragma unroll
  for (int u = 0; u < 16; ++u) {
    int i = i0 + u * 256;
    if (i < e) {
      int s = __builtin_nontemporal_load(&src[i]);
      tmp[base[d[u] >> BSH] + rk[u]] = ((d[u] & (BSZ - 1)) << 16) | s;
    }
  }
}

// one block per bucket: per-node degree + scan + cursor scatter, all in LDS.
__global__ __launch_bounds__(512) void k_bucket_build(
    const int* __restrict__ tmp, const int* __restrict__ gbase,
    int* __restrict__ rowptr, float* __restrict__ dinv,
    int* __restrict__ colarr, int n, int kb, int e) {
  __shared__ int dl[BSZ], cl[BSZ], ws[8];
  int t = threadIdx.x, b = blockIdx.x;
  int s0 = gbase[b], s1 = gbase[b + 1];
  dl[t] = 0;
  __syncthreads();
  for (int j = s0 + t; j < s1; j += 512)
    atomicAdd(&dl[((unsigned)tmp[j]) >> 16], 1);
  __syncthreads();
  int lane = t & 63, w = t >> 6;
  int v = dl[t], orig = v;
#pragma unroll
  for (int o = 1; o < 64; o <<= 1) {
    int u = __shfl_up(v, o, 64);
    if (lane >= o) v += u;
  }
  if (lane == 63) ws[w] = v;
  __syncthreads();
  if (t == 0) {
    int a = 0;
#pragma unroll
    for (int k = 0; k < 8; ++k) { int x = ws[k]; ws[k] = a; a += x; }
  }
  __syncthreads();
  int ex = ws[w] + v - orig;
  cl[t] = ex;
  int node = (b << BSH) + t;
  if (node < n) {
    rowptr[node] = s0 + ex;
    dinv[node] = rsqrtf((float)(orig + 1));  // +1 self loop
  }
  if (b == kb - 1 && t == 0) rowptr[n] = e;
  __syncthreads();
  for (int j = s0 + t; j < s1; j += 512) {
    int p = tmp[j];
    int r = atomicAdd(&cl[((unsigned)p) >> 16], 1);
    colarr[s0 + r] = p & 0xFFFF;
  }
}

// --- MFMA GEMM machinery ----------------------------------------------------
// Exact split: x = hi(bf16, trunc) + lo(bf16, trunc) + O(2^-17 |x|).
__device__ __forceinline__ void split8(const float* v, bf16x8& hi, bf16x8& lo) {
#pragma unroll
  for (int j = 0; j < 8; ++j) {
    unsigned u = __float_as_uint(v[j]);
    hi[j] = (short)(u >> 16);
    float lf = v[j] - __uint_as_float(u & 0xffff0000u);
    lo[j] = (short)(__float_as_uint(lf) >> 16);
  }
}

// Precompute B-operand bf16 hi/lo fragments for the 4 weight matrices.
// Slot g = ((w*8 + t)*4 + s)*64 + lane ; lane holds B[k=s*32+quad*8+j][n=16t+(lane&15)]
__global__ __launch_bounds__(256) void k_prep_w(
    const float* __restrict__ W1, const float* __restrict__ W2,
    const float* __restrict__ Wh1, short* __restrict__ fragH,
    short* __restrict__ fragL) {
  int g = blockIdx.x * 256 + threadIdx.x;
  if (g >= 4 * 2048) return;
  int w = g >> 11;
  int rem = g & 2047;
  int lane = rem & 63;
  int ts = rem >> 6;          // t*4 + s
  int t = ts >> 2, s = ts & 3;
  int n = (t << 4) + (lane & 15);
  int k0 = s * 32 + (lane >> 4) * 8;
  const float* W = (w == 0) ? W1 : (w == 1) ? W2 : (w == 2) ? Wh1 : (Wh1 + 128 * 128);
  short h[8], l[8];
#pragma unroll
  for (int j = 0; j < 8; ++j) {
    float x = W[(k0 + j) * 128 + n];
    unsigned u = __float_as_uint(x);
    h[j] = (short)(u >> 16);
    float lf = x - __uint_as_float(u & 0xffff0000u);
    l[j] = (short)(__float_as_uint(lf) >> 16);
  }
  ((int4*)fragH)[g] = *(int4*)h;
  ((int4*)fragL)[g] = *(int4*)l;
}

// C16[n,128] = fp16( rowscale * (X[n,128] @ W) ) via 16x16x32 bf16 MFMA.
// One wave = 16 rows x 128 cols. No LDS, no barriers.
__global__ __launch_bounds__(256) void k_gemm_mfma(
    const float* __restrict__ X, const short* __restrict__ fragH,
    const short* __restrict__ fragL, const float* __restrict__ rowscale,
    __half* __restrict__ C16, int n) {
  int wid = threadIdx.x >> 6, lane = threadIdx.x & 63;
  int r0 = (blockIdx.x * 4 + wid) * 16;
  if (r0 >= n) return;
  int m = lane & 15, quad = lane >> 4;
  const float* xrow = X + (size_t)(r0 + m) * 128;
  f32x4 acc[8];
#pragma unroll
  for (int t = 0; t < 8; ++t) acc[t] = (f32x4)(0.f);
  const int4* FH = (const int4*)fragH;
  const int4* FL = (const int4*)fragL;
#pragma unroll
  for (int s = 0; s < 4; ++s) {
    int k0 = s * 32 + quad * 8;
    float xv[8];
    *(float4*)&xv[0] = *(const float4*)(xrow + k0);
    *(float4*)&xv[4] = *(const float4*)(xrow + k0 + 4);
    bf16x8 ah, al;
    split8(xv, ah, al);
#pragma unroll
    for (int t = 0; t < 8; ++t) {
      int idx = (t * 4 + s) * 64 + lane;
      bf16x8 bh = *(const bf16x8*)&FH[idx];
      bf16x8 bl = *(const bf16x8*)&FL[idx];
      acc[t] = __builtin_amdgcn_mfma_f32_16x16x32_bf16(ah, bh, acc[t], 0, 0, 0);
      acc[t] = __builtin_amdgcn_mfma_f32_16x16x32_bf16(al, bh, acc[t], 0, 0, 0);
      acc[t] = __builtin_amdgcn_mfma_f32_16x16x32_bf16(ah, bl, acc[t], 0, 0, 0);
    }
  }
  // C/D layout: col = lane&15, row = quad*4 + reg   [m89-verified mapping]
  float sc[4];
#pragma unroll
  for (int r = 0; r < 4; ++r)
    sc[r] = rowscale ? rowscale[r0 + quad * 4 + r] : 1.f;
#pragma unroll
  for (int t = 0; t < 8; ++t) {
#pragma unroll
    for (int r = 0; r < 4; ++r) {
      int row = r0 + quad * 4 + r;
      C16[(size_t)row * 128 + t * 16 + m] = __float2half(acc[t][r] * sc[r]);
    }
  }
}

// Column-sliced aggregation: slice = 32 cols (16 half2) = one 64B line/row.
// blockIdx%4 = slice (round-robin XCD dispatch -> slice-local 3.2MB L2 set).
// Block = 4 waves = 4 rows; wave = 4 edge-subgroups x 16 half2-lanes.
// out[i,slice] = relu(dinv[i] * (g[i]+sum g[col]) + bias)
__global__ __launch_bounds__(256) void k_agg_s(
    const __half2* __restrict__ g2, const float* __restrict__ dinv,
    const int* __restrict__ rowptr, const int* __restrict__ col,
    const float* __restrict__ bias, float* __restrict__ out, int n) {
  int sl = blockIdx.x & 3;
  int rb = blockIdx.x >> 2;
  int wid = threadIdx.x >> 6, lane = threadIdx.x & 63;
  int i = rb * 4 + wid;
  if (i >= n) return;
  int e = lane >> 4;        // edge subgroup 0..3
  int c = sl * 16 + (lane & 15);  // global half2 column
  int beg = rowptr[i], end = rowptr[i + 1];
  float2 a0 = make_float2(0.f, 0.f), a1 = make_float2(0.f, 0.f);
  if (e == 0) a0 = __half22float2(g2[(size_t)i * 64 + c]);  // self loop once
  int j = beg;
  for (; j + 8 <= end; j += 8) {
    int s0 = __builtin_nontemporal_load(&col[j + e]);
    int s1 = __builtin_nontemporal_load(&col[j + 4 + e]);
    float2 v0 = __half22float2(g2[(size_t)s0 * 64 + c]);
    float2 v1 = __half22float2(g2[(size_t)s1 * 64 + c]);
    a0.x += v0.x; a0.y += v0.y;
    a1.x += v1.x; a1.y += v1.y;
  }
  for (; j < end; j += 4) {
    if (j + e < end) {
      int s0 = __builtin_nontemporal_load(&col[j + e]);
      float2 v0 = __half22float2(g2[(size_t)s0 * 64 + c]);
      a0.x += v0.x; a0.y += v0.y;
    }
  }
  float sx = a0.x + a1.x, sy = a0.y + a1.y;
  sx += __shfl_down(sx, 32, 64); sx += __shfl_down(sx, 16, 64);
  sy += __shfl_down(sy, 32, 64); sy += __shfl_down(sy, 16, 64);
  if (e == 0) {
    float di = dinv[i];
    float2 bi = ((const float2*)bias)[c];
    float2 o;
    o.x = fmaxf(fmaf(di, sx, bi.x), 0.f);
    o.y = fmaxf(fmaf(di, sy, bi.y), 0.f);
    ((float2*)out)[(size_t)i * 64 + c] = o;
  }
}

// one wave per pair, fp16 A/B tables, half2 per lane
__global__ __launch_bounds__(256) void k_pairs_h(
    const __half2* __restrict__ A, const __half2* __restrict__ B,
    const int* __restrict__ pairs, const float* __restrict__ bh1,
    const float* __restrict__ wh2, const float* __restrict__ bh2,
    float* __restrict__ out, int P) {
  int p = blockIdx.x * 4 + (threadIdx.x >> 6);
  int c = threadIdx.x & 63;
  if (p >= P) return;
  int p0 = pairs[2 * p], p1 = pairs[2 * p + 1];
  float2 av = __half22float2(A[(size_t)p0 * 64 + c]);
  float2 bv = __half22float2(B[(size_t)p1 * 64 + c]);
  float2 bi = ((const float2*)bh1)[c];
  float2 wv = ((const float2*)wh2)[c];
  float v0 = fmaxf(av.x + bv.x + bi.x, 0.f) * wv.x;
  float v1 = fmaxf(av.y + bv.y + bi.y, 0.f) * wv.y;
  float s = v0 + v1;
#pragma unroll
  for (int o = 32; o > 0; o >>= 1) s += __shfl_down(s, o, 64);
  if (c == 0) out[p] = s + bh2[0];
}

extern "C" void kernel_launch(void* const* d_in, const int* in_sizes, int n_in,
                              void* d_out, int out_size, void* d_ws, size_t ws_size,
                              hipStream_t stream) {
  const float* x   = (const float*)d_in[0];
  const int* ei    = (const int*)d_in[1];
  const int* pairs = (const int*)d_in[2];
  const float* W1  = (const float*)d_in[3];
  const float* b1  = (const float*)d_in[4];
  const float* W2  = (const float*)d_in[5];
  const float* b2  = (const float*)d_in[6];
  const float* Wh1 = (const float*)d_in[7];
  const float* bh1 = (const float*)d_in[8];
  const float* Wh2 = (const float*)d_in[9];
  const float* bh2 = (const float*)d_in[10];
  (void)n_in; (void)out_size; (void)ws_size;

  int N = in_sizes[0] / 128;
  int E = in_sizes[1] / 2;
  int P = in_sizes[2] / 2;
  const int* src = ei;
  const int* dst = ei + E;
  int KB = (N + BSZ - 1) >> BSH;  // buckets (98 for N=50000)

  char* wsp = (char*)d_ws;
  size_t off = 0;
  auto alloc = [&](size_t bytes) -> void* {
    void* p = wsp + off;
    off += (bytes + 255) & ~(size_t)255;
    return p;
  };
  __half* g16 = (__half*)alloc((size_t)N * 128 * 2);  // messages; reused as A16
  float* h1   = (float*)alloc((size_t)N * 128 * 4);   // reused as B16 (fp16)
  float* h2   = (float*)alloc((size_t)N * 128 * 4);
  float* dinv = (float*)alloc((size_t)N * 4);
  int* rowptr = (int*)alloc((size_t)(N + 1) * 4);
  int* colarr = (int*)alloc((size_t)E * 4);
  int* tmp    = (int*)alloc((size_t)E * 4);           // packed bucketed edges
  short* fragH = (short*)alloc(4 * 2048 * 8 * 2);     // 128KB
  short* fragL = (short*)alloc(4 * 2048 * 8 * 2);     // 128KB
  int* gcnt  = (int*)alloc((size_t)(KB + 1) * 4);
  int* gbase = (int*)alloc((size_t)(KB + 1) * 4);
  int* gcur  = (int*)alloc((size_t)(KB + 1) * 4);
  __half* A16 = g16;            // g16 dead by the time head runs
  __half* B16 = (__half*)h1;    // h1 dead after conv2 gemm
  // per-W frag bases (2048 slots * 8 shorts each)
  short* fH_W1 = fragH + 0 * 16384;  short* fL_W1 = fragL + 0 * 16384;
  short* fH_W2 = fragH + 1 * 16384;  short* fL_W2 = fragL + 1 * 16384;
  short* fH_Wa = fragH + 2 * 16384;  short* fL_Wa = fragL + 2 * 16384;
  short* fH_Wb = fragH + 3 * 16384;  short* fL_Wb = fragL + 3 * 16384;

  // weight fragment prep (independent of CSR)
  k_prep_w<<<32, 256, 0, stream>>>(W1, W2, Wh1, fragH, fragL);

  // CSR build: hist -> scan -> multisplit -> per-bucket LDS sort
  k_zero_i32<<<1, 256, 0, stream>>>(gcnt, KB + 1);
  k_bucket_hist<<<256, 256, 0, stream>>>(dst, gcnt, E, KB);
  k_bucket_scan<<<1, 128, 0, stream>>>(gcnt, gbase, gcur, KB);
  k_multisplit<<<(E + MSB - 1) / MSB, 256, 0, stream>>>(src, dst, gcur, tmp, E, KB);
  k_bucket_build<<<KB, 512, 0, stream>>>(tmp, gbase, rowptr, dinv, colarr, N, KB, E);

  int GB = (N / 16 + 3) / 4;       // gemm: waves of 16 rows, 4 per block
  int AGB = ((N + 3) / 4) * 4;     // agg: 4 slices x ceil(N/4) row-blocks
  // conv1
  k_gemm_mfma<<<GB, 256, 0, stream>>>(x, fH_W1, fL_W1, dinv, g16, N);
  k_agg_s<<<AGB, 256, 0, stream>>>((const __half2*)g16, dinv, rowptr, colarr, b1, h1, N);
  // conv2
  k_gemm_mfma<<<GB, 256, 0, stream>>>(h1, fH_W2, fL_W2, dinv, g16, N);
  k_agg_s<<<AGB, 256, 0, stream>>>((const __half2*)g16, dinv, rowptr, colarr, b2, h2, N);
  // head: A = h2 @ Wh1_top, B = h2 @ Wh1_bot
  k_gemm_mfma<<<GB, 256, 0, stream>>>(h2, fH_Wa, fL_Wa, nullptr, A16, N);
  k_gemm_mfma<<<GB, 256, 0, stream>>>(h2, fH_Wb, fL_Wb, nullptr, B16, N);
  k_pairs_h<<<(P + 3) / 4, 256, 0, stream>>>((const __half2*)A16, (const __half2*)B16,
                                             pairs, bh1, Wh2, bh2, (float*)d_out, P);
}

// Round 8
// 541.094 us; speedup vs baseline: 1.0464x; 1.0464x over previous
//
#include <hip/hip_runtime.h>
#include <hip/hip_fp16.h>

// ---------------------------------------------------------------------------
// LinkPredictionGNN: 2x GCNConv (self-loops, sym-norm) + pair MLP head.
//   CSR build: bucket hist -> scan -> multisplit -> per-bucket LDS sort
//   g1 = fp16( dinv * (x @ W1) )                        [k_gemm_mfma]
//   h1 = relu(dinv * (gather-sum g1 + g1) + b1)         [k_agg_s slice-MAJOR]
//   g2 = fp16( dinv * (h1 @ W2) )                       [k_gemm_mfma]
//   h2 = relu(dinv * (gather-sum g2 + g2) + b2)         [k_agg_s]
//   A = fp16(h2 @ Wh1_top), B = fp16(h2 @ Wh1_bot)      [k_gemm_mfma x2]
//   out[p] = relu(A[p0]+B[p1]+bh1) . Wh2 + bh2          [pairs_h]
//
// R1/R4 lesson: random 4B global writes/atomics -> ~10x line-writeback amp,
//   and spatial block->XCD affinity tricks (blockIdx%k, XCC_ID pinning) are
//   unreliable/regressive.
// R5: CSR build = 2-level bucket sort, zero global random atomics.
// R6 FAILED: slice = blockIdx%4 interleaved slices on every XCD (FETCH up).
// R7: slice-MAJOR grid: 4 sequential phases; during each phase all XCDs
//   gather from one 3.2MB slice sub-table (< 4MB L2) -> temporal
//   partitioning needs no dispatch-mapping assumption. colarr packed u16.
// R2: fp16 message/A/B tables (absmax 4.9e-4 < 1.5e-3 threshold).
// R3: double-bf16-split MFMA GEMM (Ah.Bh+Al.Bh+Ah.Bl), no LDS/barriers.
// ---------------------------------------------------------------------------

#define BSH 9                 // log2 nodes per bucket
#define BSZ (1 << BSH)        // 512 nodes per bucket
#define MSB 4096              // edges per multisplit batch/block

typedef __attribute__((ext_vector_type(8))) short bf16x8;
typedef __attribute__((ext_vector_type(4))) float f32x4;

__global__ __launch_bounds__(256) void k_zero_i32(int* __restrict__ p, int n) {
  int i = blockIdx.x * 256 + threadIdx.x;
  if (i < n) p[i] = 0;
}

// per-block LDS histogram of dst into buckets of BSZ nodes
__global__ __launch_bounds__(256) void k_bucket_hist(const int* __restrict__ dst,
                                                     int* __restrict__ gcnt,
                                                     int e, int kb) {
  __shared__ int h[128];
  int tid = threadIdx.x;
  if (tid < kb) h[tid] = 0;
  __syncthreads();
  int stride = gridDim.x * 256;
  for (int i = blockIdx.x * 256 + tid; i < e; i += stride) {
    int d = __builtin_nontemporal_load(&dst[i]);
    atomicAdd(&h[d >> BSH], 1);
  }
  __syncthreads();
  if (tid < kb) atomicAdd(&gcnt[tid], h[tid]);
}

// 1 block, 128 threads: exclusive scan of bucket counts -> gbase, gcur
__global__ __launch_bounds__(128) void k_bucket_scan(const int* __restrict__ gcnt,
                                                     int* __restrict__ gbase,
                                                     int* __restrict__ gcur,
                                                     int kb) {
  __shared__ int ws[2];
  int t = threadIdx.x;
  int lane = t & 63, w = t >> 6;
  int v = (t < kb) ? gcnt[t] : 0;
  int orig = v;
#pragma unroll
  for (int o = 1; o < 64; o <<= 1) {
    int u = __shfl_up(v, o, 64);
    if (lane >= o) v += u;
  }
  if (lane == 63) ws[w] = v;
  __syncthreads();
  int ex = ((w == 1) ? ws[0] : 0) + v - orig;
  if (t < kb) { gbase[t] = ex; gcur[t] = ex; }
  if (t == kb - 1) gbase[kb] = ex + orig;
}

// multisplit: one 4096-edge batch per block; per-edge intra-bucket rank from
// LDS histogram; one global atomic per bucket per batch reserves a contiguous
// segment; packed edge = (d_local << 16) | src   [valid: src < 65536]
__global__ __launch_bounds__(256) void k_multisplit(const int* __restrict__ src,
                                                    const int* __restrict__ dst,
                                                    int* __restrict__ gcur,
                                                    int* __restrict__ tmp,
                                                    int e, int kb) {
  __shared__ int h[128], base[128];
  int tid = threadIdx.x;
  if (tid < kb) h[tid] = 0;
  __syncthreads();
  int i0 = blockIdx.x * MSB + tid;
  int d[16], rk[16];
#pragma unroll
  for (int u = 0; u < 16; ++u) {
    int i = i0 + u * 256;
    if (i < e) {
      d[u] = __builtin_nontemporal_load(&dst[i]);
      rk[u] = atomicAdd(&h[d[u] >> BSH], 1);
    }
  }
  __syncthreads();
  if (tid < kb && h[tid] > 0) base[tid] = atomicAdd(&gcur[tid], h[tid]);
  __syncthreads();
#pragma unroll
  for (int u = 0; u < 16; ++u) {
    int i = i0 + u * 256;
    if (i < e) {
      int s = __builtin_nontemporal_load(&src[i]);
      tmp[base[d[u] >> BSH] + rk[u]] = ((d[u] & (BSZ - 1)) << 16) | s;
    }
  }
}

// one block per bucket: per-node degree + scan + cursor scatter, all in LDS.
// colarr written as u16 (src < 65536), bucket-local so no write-amp.
__global__ __launch_bounds__(512) void k_bucket_build(
    const int* __restrict__ tmp, const int* __restrict__ gbase,
    int* __restrict__ rowptr, float* __restrict__ dinv,
    unsigned short* __restrict__ colarr, int n, int kb, int e) {
  __shared__ int dl[BSZ], cl[BSZ], ws[8];
  int t = threadIdx.x, b = blockIdx.x;
  int s0 = gbase[b], s1 = gbase[b + 1];
  dl[t] = 0;
  __syncthreads();
  for (int j = s0 + t; j < s1; j += 512)
    atomicAdd(&dl[((unsigned)tmp[j]) >> 16], 1);
  __syncthreads();
  int lane = t & 63, w = t >> 6;
  int v = dl[t], orig = v;
#pragma unroll
  for (int o = 1; o < 64; o <<= 1) {
    int u = __shfl_up(v, o, 64);
    if (lane >= o) v += u;
  }
  if (lane == 63) ws[w] = v;
  __syncthreads();
  if (t == 0) {
    int a = 0;
#pragma unroll
    for (int k = 0; k < 8; ++k) { int x = ws[k]; ws[k] = a; a += x; }
  }
  __syncthreads();
  int ex = ws[w] + v - orig;
  cl[t] = ex;
  int node = (b << BSH) + t;
  if (node < n) {
    rowptr[node] = s0 + ex;
    dinv[node] = rsqrtf((float)(orig + 1));  // +1 self loop
  }
  if (b == kb - 1 && t == 0) rowptr[n] = e;
  __syncthreads();
  for (int j = s0 + t; j < s1; j += 512) {
    int p = tmp[j];
    int r = atomicAdd(&cl[((unsigned)p) >> 16], 1);
    colarr[s0 + r] = (unsigned short)(p & 0xFFFF);
  }
}

// --- MFMA GEMM machinery ----------------------------------------------------
// Exact split: x = hi(bf16, trunc) + lo(bf16, trunc) + O(2^-17 |x|).
__device__ __forceinline__ void split8(const float* v, bf16x8& hi, bf16x8& lo) {
#pragma unroll
  for (int j = 0; j < 8; ++j) {
    unsigned u = __float_as_uint(v[j]);
    hi[j] = (short)(u >> 16);
    float lf = v[j] - __uint_as_float(u & 0xffff0000u);
    lo[j] = (short)(__float_as_uint(lf) >> 16);
  }
}

// Precompute B-operand bf16 hi/lo fragments for the 4 weight matrices.
// Slot g = ((w*8 + t)*4 + s)*64 + lane ; lane holds B[k=s*32+quad*8+j][n=16t+(lane&15)]
__global__ __launch_bounds__(256) void k_prep_w(
    const float* __restrict__ W1, const float* __restrict__ W2,
    const float* __restrict__ Wh1, short* __restrict__ fragH,
    short* __restrict__ fragL) {
  int g = blockIdx.x * 256 + threadIdx.x;
  if (g >= 4 * 2048) return;
  int w = g >> 11;
  int rem = g & 2047;
  int lane = rem & 63;
  int ts = rem >> 6;          // t*4 + s
  int t = ts >> 2, s = ts & 3;
  int n = (t << 4) + (lane & 15);
  int k0 = s * 32 + (lane >> 4) * 8;
  const float* W = (w == 0) ? W1 : (w == 1) ? W2 : (w == 2) ? Wh1 : (Wh1 + 128 * 128);
  short h[8], l[8];
#pragma unroll
  for (int j = 0; j < 8; ++j) {
    float x = W[(k0 + j) * 128 + n];
    unsigned u = __float_as_uint(x);
    h[j] = (short)(u >> 16);
    float lf = x - __uint_as_float(u & 0xffff0000u);
    l[j] = (short)(__float_as_uint(lf) >> 16);
  }
  ((int4*)fragH)[g] = *(int4*)h;
  ((int4*)fragL)[g] = *(int4*)l;
}

// C16[n,128] = fp16( rowscale * (X[n,128] @ W) ) via 16x16x32 bf16 MFMA.
// One wave = 16 rows x 128 cols. No LDS, no barriers.
__global__ __launch_bounds__(256) void k_gemm_mfma(
    const float* __restrict__ X, const short* __restrict__ fragH,
    const short* __restrict__ fragL, const float* __restrict__ rowscale,
    __half* __restrict__ C16, int n) {
  int wid = threadIdx.x >> 6, lane = threadIdx.x & 63;
  int r0 = (blockIdx.x * 4 + wid) * 16;
  if (r0 >= n) return;
  int m = lane & 15, quad = lane >> 4;
  const float* xrow = X + (size_t)(r0 + m) * 128;
  f32x4 acc[8];
#pragma unroll
  for (int t = 0; t < 8; ++t) acc[t] = (f32x4)(0.f);
  const int4* FH = (const int4*)fragH;
  const int4* FL = (const int4*)fragL;
#pragma unroll
  for (int s = 0; s < 4; ++s) {
    int k0 = s * 32 + quad * 8;
    float xv[8];
    *(float4*)&xv[0] = *(const float4*)(xrow + k0);
    *(float4*)&xv[4] = *(const float4*)(xrow + k0 + 4);
    bf16x8 ah, al;
    split8(xv, ah, al);
#pragma unroll
    for (int t = 0; t < 8; ++t) {
      int idx = (t * 4 + s) * 64 + lane;
      bf16x8 bh = *(const bf16x8*)&FH[idx];
      bf16x8 bl = *(const bf16x8*)&FL[idx];
      acc[t] = __builtin_amdgcn_mfma_f32_16x16x32_bf16(ah, bh, acc[t], 0, 0, 0);
      acc[t] = __builtin_amdgcn_mfma_f32_16x16x32_bf16(al, bh, acc[t], 0, 0, 0);
      acc[t] = __builtin_amdgcn_mfma_f32_16x16x32_bf16(ah, bl, acc[t], 0, 0, 0);
    }
  }
  // C/D layout: col = lane&15, row = quad*4 + reg   [m89-verified mapping]
  float sc[4];
#pragma unroll
  for (int r = 0; r < 4; ++r)
    sc[r] = rowscale ? rowscale[r0 + quad * 4 + r] : 1.f;
#pragma unroll
  for (int t = 0; t < 8; ++t) {
#pragma unroll
    for (int r = 0; r < 4; ++r) {
      int row = r0 + quad * 4 + r;
      C16[(size_t)row * 128 + t * 16 + m] = __float2half(acc[t][r] * sc[r]);
    }
  }
}

// Column-sliced aggregation, slice-MAJOR grid: blocks [sl*rb, (sl+1)*rb) all
// handle slice sl (32 cols = one 64B line per gathered row). Hardware
// dispatches blocks roughly in order -> during each phase every XCD's L2
// holds only that slice's 3.2MB sub-table. Wave = 4 edge-subgroups x 16
// half2-lanes; block = 4 rows.
__global__ __launch_bounds__(256) void k_agg_s(
    const __half2* __restrict__ g2, const float* __restrict__ dinv,
    const int* __restrict__ rowptr, const unsigned short* __restrict__ col,
    const float* __restrict__ bias, float* __restrict__ out, int n, int rb) {
  int sl = blockIdx.x / rb;
  int rbi = blockIdx.x - sl * rb;
  int wid = threadIdx.x >> 6, lane = threadIdx.x & 63;
  int i = rbi * 4 + wid;
  if (i >= n) return;
  int e = lane >> 4;              // edge subgroup 0..3
  int c = sl * 16 + (lane & 15);  // global half2 column
  int beg = rowptr[i], end = rowptr[i + 1];
  float2 a0 = make_float2(0.f, 0.f), a1 = make_float2(0.f, 0.f);
  if (e == 0) a0 = __half22float2(g2[(size_t)i * 64 + c]);  // self loop once
  int j = beg;
  for (; j + 8 <= end; j += 8) {
    int s0 = __builtin_nontemporal_load(&col[j + e]);
    int s1 = __builtin_nontemporal_load(&col[j + 4 + e]);
    float2 v0 = __half22float2(g2[(size_t)s0 * 64 + c]);
    float2 v1 = __half22float2(g2[(size_t)s1 * 64 + c]);
    a0.x += v0.x; a0.y += v0.y;
    a1.x += v1.x; a1.y += v1.y;
  }
  for (; j < end; j += 4) {
    if (j + e < end) {
      int s0 = __builtin_nontemporal_load(&col[j + e]);
      float2 v0 = __half22float2(g2[(size_t)s0 * 64 + c]);
      a0.x += v0.x; a0.y += v0.y;
    }
  }
  float sx = a0.x + a1.x, sy = a0.y + a1.y;
  sx += __shfl_down(sx, 32, 64); sx += __shfl_down(sx, 16, 64);
  sy += __shfl_down(sy, 32, 64); sy += __shfl_down(sy, 16, 64);
  if (e == 0) {
    float di = dinv[i];
    float2 bi = ((const float2*)bias)[c];
    float2 o;
    o.x = fmaxf(fmaf(di, sx, bi.x), 0.f);
    o.y = fmaxf(fmaf(di, sy, bi.y), 0.f);
    ((float2*)out)[(size_t)i * 64 + c] = o;
  }
}

// one wave per pair, fp16 A/B tables, half2 per lane
__global__ __launch_bounds__(256) void k_pairs_h(
    const __half2* __restrict__ A, const __half2* __restrict__ B,
    const int* __restrict__ pairs, const float* __restrict__ bh1,
    const float* __restrict__ wh2, const float* __restrict__ bh2,
    float* __restrict__ out, int P) {
  int p = blockIdx.x * 4 + (threadIdx.x >> 6);
  int c = threadIdx.x & 63;
  if (p >= P) return;
  int p0 = pairs[2 * p], p1 = pairs[2 * p + 1];
  float2 av = __half22float2(A[(size_t)p0 * 64 + c]);
  float2 bv = __half22float2(B[(size_t)p1 * 64 + c]);
  float2 bi = ((const float2*)bh1)[c];
  float2 wv = ((const float2*)wh2)[c];
  float v0 = fmaxf(av.x + bv.x + bi.x, 0.f) * wv.x;
  float v1 = fmaxf(av.y + bv.y + bi.y, 0.f) * wv.y;
  float s = v0 + v1;
#pragma unroll
  for (int o = 32; o > 0; o >>= 1) s += __shfl_down(s, o, 64);
  if (c == 0) out[p] = s + bh2[0];
}

extern "C" void kernel_launch(void* const* d_in, const int* in_sizes, int n_in,
                              void* d_out, int out_size, void* d_ws, size_t ws_size,
                              hipStream_t stream) {
  const float* x   = (const float*)d_in[0];
  const int* ei    = (const int*)d_in[1];
  const int* pairs = (const int*)d_in[2];
  const float* W1  = (const float*)d_in[3];
  const float* b1  = (const float*)d_in[4];
  const float* W2  = (const float*)d_in[5];
  const float* b2  = (const float*)d_in[6];
  const float* Wh1 = (const float*)d_in[7];
  const float* bh1 = (const float*)d_in[8];
  const float* Wh2 = (const float*)d_in[9];
  const float* bh2 = (const float*)d_in[10];
  (void)n_in; (void)out_size; (void)ws_size;

  int N = in_sizes[0] / 128;
  int E = in_sizes[1] / 2;
  int P = in_sizes[2] / 2;
  const int* src = ei;
  const int* dst = ei + E;
  int KB = (N + BSZ - 1) >> BSH;  // buckets (98 for N=50000)

  char* wsp = (char*)d_ws;
  size_t off = 0;
  auto alloc = [&](size_t bytes) -> void* {
    void* p = wsp + off;
    off += (bytes + 255) & ~(size_t)255;
    return p;
  };
  __half* g16 = (__half*)alloc((size_t)N * 128 * 2);  // messages; reused as A16
  float* h1   = (float*)alloc((size_t)N * 128 * 4);   // reused as B16 (fp16)
  float* h2   = (float*)alloc((size_t)N * 128 * 4);
  float* dinv = (float*)alloc((size_t)N * 4);
  int* rowptr = (int*)alloc((size_t)(N + 1) * 4);
  unsigned short* colarr = (unsigned short*)alloc((size_t)E * 2);
  int* tmp    = (int*)alloc((size_t)E * 4);           // packed bucketed edges
  short* fragH = (short*)alloc(4 * 2048 * 8 * 2);     // 128KB
  short* fragL = (short*)alloc(4 * 2048 * 8 * 2);     // 128KB
  int* gcnt  = (int*)alloc((size_t)(KB + 1) * 4);
  int* gbase = (int*)alloc((size_t)(KB + 1) * 4);
  int* gcur  = (int*)alloc((size_t)(KB + 1) * 4);
  __half* A16 = g16;            // g16 dead by the time head runs
  __half* B16 = (__half*)h1;    // h1 dead after conv2 gemm
  // per-W frag bases (2048 slots * 8 shorts each)
  short* fH_W1 = fragH + 0 * 16384;  short* fL_W1 = fragL + 0 * 16384;
  short* fH_W2 = fragH + 1 * 16384;  short* fL_W2 = fragL + 1 * 16384;
  short* fH_Wa = fragH + 2 * 16384;  short* fL_Wa = fragL + 2 * 16384;
  short* fH_Wb = fragH + 3 * 16384;  short* fL_Wb = fragL + 3 * 16384;

  // weight fragment prep (independent of CSR)
  k_prep_w<<<32, 256, 0, stream>>>(W1, W2, Wh1, fragH, fragL);

  // CSR build: hist -> scan -> multisplit -> per-bucket LDS sort
  k_zero_i32<<<1, 256, 0, stream>>>(gcnt, KB + 1);
  k_bucket_hist<<<256, 256, 0, stream>>>(dst, gcnt, E, KB);
  k_bucket_scan<<<1, 128, 0, stream>>>(gcnt, gbase, gcur, KB);
  k_multisplit<<<(E + MSB - 1) / MSB, 256, 0, stream>>>(src, dst, gcur, tmp, E, KB);
  k_bucket_build<<<KB, 512, 0, stream>>>(tmp, gbase, rowptr, dinv, colarr, N, KB, E);

  int GB = (N / 16 + 3) / 4;       // gemm: waves of 16 rows, 4 per block
  int RB = (N + 3) / 4;            // agg row-blocks per slice
  int AGB = 4 * RB;                // slice-major: 4 phases
  // conv1
  k_gemm_mfma<<<GB, 256, 0, stream>>>(x, fH_W1, fL_W1, dinv, g16, N);
  k_agg_s<<<AGB, 256, 0, stream>>>((const __half2*)g16, dinv, rowptr, colarr, b1, h1, N, RB);
  // conv2
  k_gemm_mfma<<<GB, 256, 0, stream>>>(h1, fH_W2, fL_W2, dinv, g16, N);
  k_agg_s<<<AGB, 256, 0, stream>>>((const __half2*)g16, dinv, rowptr, colarr, b2, h2, N, RB);
  // head: A = h2 @ Wh1_top, B = h2 @ Wh1_bot
  k_gemm_mfma<<<GB, 256, 0, stream>>>(h2, fH_Wa, fL_Wa, nullptr, A16, N);
  k_gemm_mfma<<<GB, 256, 0, stream>>>(h2, fH_Wb, fL_Wb, nullptr, B16, N);
  k_pairs_h<<<(P + 3) / 4, 256, 0, stream>>>((const __half2*)A16, (const __half2*)B16,
                                             pairs, bh1, Wh2, bh2, (float*)d_out, P);
}

// Round 9
// 404.533 us; speedup vs baseline: 1.3997x; 1.3376x over previous
//
#include <hip/hip_runtime.h>
#include <hip/hip_fp16.h>

// ---------------------------------------------------------------------------
// LinkPredictionGNN: 2x GCNConv (self-loops, sym-norm) + pair MLP head.
//   CSR build: bucket hist -> scan -> multisplit -> per-bucket LDS sort
//   g1 = fp16( dinv * (x @ W1) )                        [k_gemm_mfma]
//   h1 = relu(dinv * (gather-sum g1 + g1) + b1)         [k_agg_h]
//   g2 = fp16( dinv * (h1 @ W2) )                       [k_gemm_mfma]
//   h2 = relu(dinv * (gather-sum g2 + g2) + b2)         [k_agg_h]
//   A = fp16(h2 @ Wh1_top), B = fp16(h2 @ Wh1_bot)      [k_gemm_mfma x2]
//   out[p] = relu(A[p0]+B[p1]+bh1) . Wh2 + bh2          [pairs_h]
//
// R1/R4 lesson: random 4B global writes/atomics -> ~10x line-writeback amp;
//   spatial XCD-affinity tricks (blockIdx%k, XCC_ID pin) regress.
// R5: CSR build = 2-level bucket sort, zero global random atomics.
// R6/R7 FAILED: column-sliced gather (interleaved AND slice-major) -> FETCH
//   unchanged/up; phases overlap fully. L2 hit ~58% on the 12.8MB random
//   gather table is the practical floor for pull-based agg. REVERTED to the
//   R5 full-row k_agg_h (78us known-good), colarr now u16.
// R8: gemm X-loads were 16-way scattered (512B-strided rows per quad-group).
//   Now staged: coalesced float2 global->LDS tile (stride 132 = 2-way bank
//   aliasing = free), fragments fed from LDS. One barrier per block.
// R2: fp16 message/A/B tables (absmax 4.9e-4 < 1.5e-3 threshold).
// R3: double-bf16-split MFMA GEMM (Ah.Bh+Al.Bh+Ah.Bl), no epilogue LDS.
// ---------------------------------------------------------------------------

#define BSH 9                 // log2 nodes per bucket
#define BSZ (1 << BSH)        // 512 nodes per bucket
#define MSB 4096              // edges per multisplit batch/block
#define XPAD 132              // LDS row stride (floats): 8B-aligned, 2-way banks

typedef __attribute__((ext_vector_type(8))) short bf16x8;
typedef __attribute__((ext_vector_type(4))) float f32x4;

__global__ __launch_bounds__(256) void k_zero_i32(int* __restrict__ p, int n) {
  int i = blockIdx.x * 256 + threadIdx.x;
  if (i < n) p[i] = 0;
}

// per-block LDS histogram of dst into buckets of BSZ nodes
__global__ __launch_bounds__(256) void k_bucket_hist(const int* __restrict__ dst,
                                                     int* __restrict__ gcnt,
                                                     int e, int kb) {
  __shared__ int h[128];
  int tid = threadIdx.x;
  if (tid < kb) h[tid] = 0;
  __syncthreads();
  int stride = gridDim.x * 256;
  for (int i = blockIdx.x * 256 + tid; i < e; i += stride) {
    int d = __builtin_nontemporal_load(&dst[i]);
    atomicAdd(&h[d >> BSH], 1);
  }
  __syncthreads();
  if (tid < kb) atomicAdd(&gcnt[tid], h[tid]);
}

// 1 block, 128 threads: exclusive scan of bucket counts -> gbase, gcur
__global__ __launch_bounds__(128) void k_bucket_scan(const int* __restrict__ gcnt,
                                                     int* __restrict__ gbase,
                                                     int* __restrict__ gcur,
                                                     int kb) {
  __shared__ int ws[2];
  int t = threadIdx.x;
  int lane = t & 63, w = t >> 6;
  int v = (t < kb) ? gcnt[t] : 0;
  int orig = v;
#pragma unroll
  for (int o = 1; o < 64; o <<= 1) {
    int u = __shfl_up(v, o, 64);
    if (lane >= o) v += u;
  }
  if (lane == 63) ws[w] = v;
  __syncthreads();
  int ex = ((w == 1) ? ws[0] : 0) + v - orig;
  if (t < kb) { gbase[t] = ex; gcur[t] = ex; }
  if (t == kb - 1) gbase[kb] = ex + orig;
}

// multisplit: one 4096-edge batch per block; per-edge intra-bucket rank from
// LDS histogram; one global atomic per bucket per batch reserves a contiguous
// segment; packed edge = (d_local << 16) | src   [valid: src < 65536]
__global__ __launch_bounds__(256) void k_multisplit(const int* __restrict__ src,
                                                    const int* __restrict__ dst,
                                                    int* __restrict__ gcur,
                                                    int* __restrict__ tmp,
                                                    int e, int kb) {
  __shared__ int h[128], base[128];
  int tid = threadIdx.x;
  if (tid < kb) h[tid] = 0;
  __syncthreads();
  int i0 = blockIdx.x * MSB + tid;
  int d[16], rk[16];
#pragma unroll
  for (int u = 0; u < 16; ++u) {
    int i = i0 + u * 256;
    if (i < e) {
      d[u] = __builtin_nontemporal_load(&dst[i]);
      rk[u] = atomicAdd(&h[d[u] >> BSH], 1);
    }
  }
  __syncthreads();
  if (tid < kb && h[tid] > 0) base[tid] = atomicAdd(&gcur[tid], h[tid]);
  __syncthreads();
#pragma unroll
  for (int u = 0; u < 16; ++u) {
    int i = i0 + u * 256;
    if (i < e) {
      int s = __builtin_nontemporal_load(&src[i]);
      tmp[base[d[u] >> BSH] + rk[u]] = ((d[u] & (BSZ - 1)) << 16) | s;
    }
  }
}

// one block per bucket: per-node degree + scan + cursor scatter, all in LDS.
// colarr written as u16 (src < 65536), bucket-local so no write-amp.
__global__ __launch_bounds__(512) void k_bucket_build(
    const int* __restrict__ tmp, const int* __restrict__ gbase,
    int* __restrict__ rowptr, float* __restrict__ dinv,
    unsigned short* __restrict__ colarr, int n, int kb, int e) {
  __shared__ int dl[BSZ], cl[BSZ], ws[8];
  int t = threadIdx.x, b = blockIdx.x;
  int s0 = gbase[b], s1 = gbase[b + 1];
  dl[t] = 0;
  __syncthreads();
  for (int j = s0 + t; j < s1; j += 512)
    atomicAdd(&dl[((unsigned)tmp[j]) >> 16], 1);
  __syncthreads();
  int lane = t & 63, w = t >> 6;
  int v = dl[t], orig = v;
#pragma unroll
  for (int o = 1; o < 64; o <<= 1) {
    int u = __shfl_up(v, o, 64);
    if (lane >= o) v += u;
  }
  if (lane == 63) ws[w] = v;
  __syncthreads();
  if (t == 0) {
    int a = 0;
#pragma unroll
    for (int k = 0; k < 8; ++k) { int x = ws[k]; ws[k] = a; a += x; }
  }
  __syncthreads();
  int ex = ws[w] + v - orig;
  cl[t] = ex;
  int node = (b << BSH) + t;
  if (node < n) {
    rowptr[node] = s0 + ex;
    dinv[node] = rsqrtf((float)(orig + 1));  // +1 self loop
  }
  if (b == kb - 1 && t == 0) rowptr[n] = e;
  __syncthreads();
  for (int j = s0 + t; j < s1; j += 512) {
    int p = tmp[j];
    int r = atomicAdd(&cl[((unsigned)p) >> 16], 1);
    colarr[s0 + r] = (unsigned short)(p & 0xFFFF);
  }
}

// --- MFMA GEMM machinery ----------------------------------------------------
// Exact split: x = hi(bf16, trunc) + lo(bf16, trunc) + O(2^-17 |x|).
__device__ __forceinline__ void split8(const float* v, bf16x8& hi, bf16x8& lo) {
#pragma unroll
  for (int j = 0; j < 8; ++j) {
    unsigned u = __float_as_uint(v[j]);
    hi[j] = (short)(u >> 16);
    float lf = v[j] - __uint_as_float(u & 0xffff0000u);
    lo[j] = (short)(__float_as_uint(lf) >> 16);
  }
}

// Precompute B-operand bf16 hi/lo fragments for the 4 weight matrices.
// Slot g = ((w*8 + t)*4 + s)*64 + lane ; lane holds B[k=s*32+quad*8+j][n=16t+(lane&15)]
__global__ __launch_bounds__(256) void k_prep_w(
    const float* __restrict__ W1, const float* __restrict__ W2,
    const float* __restrict__ Wh1, short* __restrict__ fragH,
    short* __restrict__ fragL) {
  int g = blockIdx.x * 256 + threadIdx.x;
  if (g >= 4 * 2048) return;
  int w = g >> 11;
  int rem = g & 2047;
  int lane = rem & 63;
  int ts = rem >> 6;          // t*4 + s
  int t = ts >> 2, s = ts & 3;
  int n = (t << 4) + (lane & 15);
  int k0 = s * 32 + (lane >> 4) * 8;
  const float* W = (w == 0) ? W1 : (w == 1) ? W2 : (w == 2) ? Wh1 : (Wh1 + 128 * 128);
  short h[8], l[8];
#pragma unroll
  for (int j = 0; j < 8; ++j) {
    float x = W[(k0 + j) * 128 + n];
    unsigned u = __float_as_uint(x);
    h[j] = (short)(u >> 16);
    float lf = x - __uint_as_float(u & 0xffff0000u);
    l[j] = (short)(__float_as_uint(lf) >> 16);
  }
  ((int4*)fragH)[g] = *(int4*)h;
  ((int4*)fragL)[g] = *(int4*)l;
}

// C16[n,128] = fp16( rowscale * (X[n,128] @ W) ) via 16x16x32 bf16 MFMA.
// Block = 64 rows (4 waves x 16). X-tile staged in LDS with coalesced
// float2 loads; fragments fed from LDS (stride 132 -> 2-way banks, free).
__global__ __launch_bounds__(256) void k_gemm_mfma(
    const float* __restrict__ X, const short* __restrict__ fragH,
    const short* __restrict__ fragL, const float* __restrict__ rowscale,
    __half* __restrict__ C16, int n) {
  __shared__ float sX[64 * XPAD];  // ~33.8 KB
  int tid = threadIdx.x;
  int row0 = blockIdx.x * 64;
  // stage 64 rows x 128 floats, coalesced: thread t -> float2 element t
  const float2* X2 = (const float2*)(X + (size_t)row0 * 128);
#pragma unroll
  for (int it = 0; it < 16; ++it) {
    int t = it * 256 + tid;           // 0..4095
    int r = t >> 6, c2 = t & 63;      // 64 float2 per row
    int gr = row0 + r;
    float2 v = (gr < n) ? X2[t] : make_float2(0.f, 0.f);
    *(float2*)&sX[r * XPAD + c2 * 2] = v;
  }
  __syncthreads();
  int wid = tid >> 6, lane = tid & 63;
  int r0 = row0 + wid * 16;
  if (r0 >= n) return;
  int m = lane & 15, quad = lane >> 4;
  const float* xrow = sX + (wid * 16 + m) * XPAD;
  f32x4 acc[8];
#pragma unroll
  for (int t = 0; t < 8; ++t) acc[t] = (f32x4)(0.f);
  const int4* FH = (const int4*)fragH;
  const int4* FL = (const int4*)fragL;
#pragma unroll
  for (int s = 0; s < 4; ++s) {
    int k0 = s * 32 + quad * 8;
    float xv[8];
    *(float2*)&xv[0] = *(const float2*)(xrow + k0);
    *(float2*)&xv[2] = *(const float2*)(xrow + k0 + 2);
    *(float2*)&xv[4] = *(const float2*)(xrow + k0 + 4);
    *(float2*)&xv[6] = *(const float2*)(xrow + k0 + 6);
    bf16x8 ah, al;
    split8(xv, ah, al);
#pragma unroll
    for (int t = 0; t < 8; ++t) {
      int idx = (t * 4 + s) * 64 + lane;
      bf16x8 bh = *(const bf16x8*)&FH[idx];
      bf16x8 bl = *(const bf16x8*)&FL[idx];
      acc[t] = __builtin_amdgcn_mfma_f32_16x16x32_bf16(ah, bh, acc[t], 0, 0, 0);
      acc[t] = __builtin_amdgcn_mfma_f32_16x16x32_bf16(al, bh, acc[t], 0, 0, 0);
      acc[t] = __builtin_amdgcn_mfma_f32_16x16x32_bf16(ah, bl, acc[t], 0, 0, 0);
    }
  }
  // C/D layout: col = lane&15, row = quad*4 + reg   [m89-verified mapping]
  float sc[4];
#pragma unroll
  for (int r = 0; r < 4; ++r)
    sc[r] = rowscale ? rowscale[r0 + quad * 4 + r] : 1.f;
#pragma unroll
  for (int t = 0; t < 8; ++t) {
#pragma unroll
    for (int r = 0; r < 4; ++r) {
      int row = r0 + quad * 4 + r;
      C16[(size_t)row * 128 + t * 16 + m] = __float2half(acc[t][r] * sc[r]);
    }
  }
}

// out[i,:] = relu(dinv[i] * (g[i,:] + sum_{e in row i} g[col[e],:]) + bias)
// fp16 message table; 64 lanes per row, one half2 (2 cols) per lane.
// [R5 known-good structure; col is u16]
__global__ __launch_bounds__(256) void k_agg_h(
    const __half2* __restrict__ g2, const float* __restrict__ dinv,
    const int* __restrict__ rowptr, const unsigned short* __restrict__ col,
    const float* __restrict__ bias, float* __restrict__ out, int n) {
  int i = blockIdx.x * 4 + (threadIdx.x >> 6);
  int c = threadIdx.x & 63;  // half2 column index
  if (i >= n) return;
  float2 a0 = __half22float2(g2[(size_t)i * 64 + c]);  // self loop
  float2 a1 = make_float2(0.f, 0.f);
  float2 a2 = make_float2(0.f, 0.f);
  float2 a3 = make_float2(0.f, 0.f);
  int beg = rowptr[i], end = rowptr[i + 1];
  int j = beg;
  for (; j + 4 <= end; j += 4) {
    int s0 = __builtin_nontemporal_load(&col[j]);
    int s1 = __builtin_nontemporal_load(&col[j + 1]);
    int s2 = __builtin_nontemporal_load(&col[j + 2]);
    int s3 = __builtin_nontemporal_load(&col[j + 3]);
    float2 v0 = __half22float2(g2[(size_t)s0 * 64 + c]);
    float2 v1 = __half22float2(g2[(size_t)s1 * 64 + c]);
    float2 v2 = __half22float2(g2[(size_t)s2 * 64 + c]);
    float2 v3 = __half22float2(g2[(size_t)s3 * 64 + c]);
    a0.x += v0.x; a0.y += v0.y;
    a1.x += v1.x; a1.y += v1.y;
    a2.x += v2.x; a2.y += v2.y;
    a3.x += v3.x; a3.y += v3.y;
  }
  for (; j < end; ++j) {
    int s0 = __builtin_nontemporal_load(&col[j]);
    float2 v = __half22float2(g2[(size_t)s0 * 64 + c]);
    a0.x += v.x; a0.y += v.y;
  }
  float di = dinv[i];
  float2 bi = ((const float2*)bias)[c];
  float2 o;
  o.x = fmaxf(fmaf(di, (a0.x + a1.x) + (a2.x + a3.x), bi.x), 0.f);
  o.y = fmaxf(fmaf(di, (a0.y + a1.y) + (a2.y + a3.y), bi.y), 0.f);
  ((float2*)out)[(size_t)i * 64 + c] = o;
}

// one wave per pair, fp16 A/B tables, half2 per lane
__global__ __launch_bounds__(256) void k_pairs_h(
    const __half2* __restrict__ A, const __half2* __restrict__ B,
    const int* __restrict__ pairs, const float* __restrict__ bh1,
    const float* __restrict__ wh2, const float* __restrict__ bh2,
    float* __restrict__ out, int P) {
  int p = blockIdx.x * 4 + (threadIdx.x >> 6);
  int c = threadIdx.x & 63;
  if (p >= P) return;
  int p0 = pairs[2 * p], p1 = pairs[2 * p + 1];
  float2 av = __half22float2(A[(size_t)p0 * 64 + c]);
  float2 bv = __half22float2(B[(size_t)p1 * 64 + c]);
  float2 bi = ((const float2*)bh1)[c];
  float2 wv = ((const float2*)wh2)[c];
  float v0 = fmaxf(av.x + bv.x + bi.x, 0.f) * wv.x;
  float v1 = fmaxf(av.y + bv.y + bi.y, 0.f) * wv.y;
  float s = v0 + v1;
#pragma unroll
  for (int o = 32; o > 0; o >>= 1) s += __shfl_down(s, o, 64);
  if (c == 0) out[p] = s + bh2[0];
}

extern "C" void kernel_launch(void* const* d_in, const int* in_sizes, int n_in,
                              void* d_out, int out_size, void* d_ws, size_t ws_size,
                              hipStream_t stream) {
  const float* x   = (const float*)d_in[0];
  const int* ei    = (const int*)d_in[1];
  const int* pairs = (const int*)d_in[2];
  const float* W1  = (const float*)d_in[3];
  const float* b1  = (const float*)d_in[4];
  const float* W2  = (const float*)d_in[5];
  const float* b2  = (const float*)d_in[6];
  const float* Wh1 = (const float*)d_in[7];
  const float* bh1 = (const float*)d_in[8];
  const float* Wh2 = (const float*)d_in[9];
  const float* bh2 = (const float*)d_in[10];
  (void)n_in; (void)out_size; (void)ws_size;

  int N = in_sizes[0] / 128;
  int E = in_sizes[1] / 2;
  int P = in_sizes[2] / 2;
  const int* src = ei;
  const int* dst = ei + E;
  int KB = (N + BSZ - 1) >> BSH;  // buckets (98 for N=50000)

  char* wsp = (char*)d_ws;
  size_t off = 0;
  auto alloc = [&](size_t bytes) -> void* {
    void* p = wsp + off;
    off += (bytes + 255) & ~(size_t)255;
    return p;
  };
  __half* g16 = (__half*)alloc((size_t)N * 128 * 2);  // messages; reused as A16
  float* h1   = (float*)alloc((size_t)N * 128 * 4);   // reused as B16 (fp16)
  float* h2   = (float*)alloc((size_t)N * 128 * 4);
  float* dinv = (float*)alloc((size_t)N * 4);
  int* rowptr = (int*)alloc((size_t)(N + 1) * 4);
  unsigned short* colarr = (unsigned short*)alloc((size_t)E * 2);
  int* tmp    = (int*)alloc((size_t)E * 4);           // packed bucketed edges
  short* fragH = (short*)alloc(4 * 2048 * 8 * 2);     // 128KB
  short* fragL = (short*)alloc(4 * 2048 * 8 * 2);     // 128KB
  int* gcnt  = (int*)alloc((size_t)(KB + 1) * 4);
  int* gbase = (int*)alloc((size_t)(KB + 1) * 4);
  int* gcur  = (int*)alloc((size_t)(KB + 1) * 4);
  __half* A16 = g16;            // g16 dead by the time head runs
  __half* B16 = (__half*)h1;    // h1 dead after conv2 gemm
  // per-W frag bases (2048 slots * 8 shorts each)
  short* fH_W1 = fragH + 0 * 16384;  short* fL_W1 = fragL + 0 * 16384;
  short* fH_W2 = fragH + 1 * 16384;  short* fL_W2 = fragL + 1 * 16384;
  short* fH_Wa = fragH + 2 * 16384;  short* fL_Wa = fragL + 2 * 16384;
  short* fH_Wb = fragH + 3 * 16384;  short* fL_Wb = fragL + 3 * 16384;

  // weight fragment prep (independent of CSR)
  k_prep_w<<<32, 256, 0, stream>>>(W1, W2, Wh1, fragH, fragL);

  // CSR build: hist -> scan -> multisplit -> per-bucket LDS sort
  k_zero_i32<<<1, 256, 0, stream>>>(gcnt, KB + 1);
  k_bucket_hist<<<256, 256, 0, stream>>>(dst, gcnt, E, KB);
  k_bucket_scan<<<1, 128, 0, stream>>>(gcnt, gbase, gcur, KB);
  k_multisplit<<<(E + MSB - 1) / MSB, 256, 0, stream>>>(src, dst, gcur, tmp, E, KB);
  k_bucket_build<<<KB, 512, 0, stream>>>(tmp, gbase, rowptr, dinv, colarr, N, KB, E);

  int GB = (N + 63) / 64;          // gemm: 64 rows per block
  int AB = (N + 3) / 4;            // agg: 4 rows per block
  // conv1
  k_gemm_mfma<<<GB, 256, 0, stream>>>(x, fH_W1, fL_W1, dinv, g16, N);
  k_agg_h<<<AB, 256, 0, stream>>>((const __half2*)g16, dinv, rowptr, colarr, b1, h1, N);
  // conv2
  k_gemm_mfma<<<GB, 256, 0, stream>>>(h1, fH_W2, fL_W2, dinv, g16, N);
  k_agg_h<<<AB, 256, 0, stream>>>((const __half2*)g16, dinv, rowptr, colarr, b2, h2, N);
  // head: A = h2 @ Wh1_top, B = h2 @ Wh1_bot
  k_gemm_mfma<<<GB, 256, 0, stream>>>(h2, fH_Wa, fL_Wa, nullptr, A16, N);
  k_gemm_mfma<<<GB, 256, 0, stream>>>(h2, fH_Wb, fL_Wb, nullptr, B16, N);
  k_pairs_h<<<(P + 3) / 4, 256, 0, stream>>>((const __half2*)A16, (const __half2*)B16,
                                             pairs, bh1, Wh2, bh2, (float*)d_out, P);
}

// Round 10
// 385.524 us; speedup vs baseline: 1.4687x; 1.0493x over previous
//
#include <hip/hip_runtime.h>
#include <hip/hip_fp16.h>

// ---------------------------------------------------------------------------
// LinkPredictionGNN: 2x GCNConv (self-loops, sym-norm) + pair MLP head.
//   CSR build: bucket hist -> scan -> multisplit -> per-bucket LDS sort
//   g1 = fp16( dinv * (x @ W1) )                        [k_gemm_mfma]
//   h1 = relu(dinv * (gather-sum g1 + g1) + b1)         [k_agg_h]
//   g2 = fp16( dinv * (h1 @ W2) )                       [k_gemm_mfma]
//   h2 = relu(dinv * (gather-sum g2 + g2) + b2)         [k_agg_h]
//   A,B = fp16(h2 @ Wh1_top), fp16(h2 @ Wh1_bot)        [k_gemm_dual]
//   out[p] = relu(A[p0]+B[p1]+bh1) . Wh2 + bh2          [pairs_h]
//
// R1/R4 lesson: random 4B global writes/atomics -> ~10x line-writeback amp;
//   spatial XCD-affinity tricks (blockIdx%k, XCC_ID pin) regress.
// R5: CSR build = 2-level bucket sort, zero global random atomics.
// R6/R7 FAILED: column-sliced gather (both interleaved and slice-major) ->
//   no FETCH reduction; XCD L2 locality is not schedulable from HIP.
// R8: gemm X-tile staged via coalesced float2->LDS (stride 132).
// R9: agg was LATENCY-bound (2.6TB/s eff, VALU 27%): now half4 gather lanes
//   (32 lanes/row, 2 edges per wave-load = 512B/instr, 8 edges in flight),
//   float4 coalesced output; pairs same treatment; head GEMMs fused (reads
//   h2 once).
// R2: fp16 message/A/B tables (absmax 4.9e-4 < 1.5e-3 threshold).
// R3: double-bf16-split MFMA GEMM (Ah.Bh+Al.Bh+Ah.Bl).
// ---------------------------------------------------------------------------

#define BSH 9                 // log2 nodes per bucket
#define BSZ (1 << BSH)        // 512 nodes per bucket
#define MSB 4096              // edges per multisplit batch/block
#define XPAD 132              // LDS row stride (floats): 8B-aligned, 2-way banks

typedef __attribute__((ext_vector_type(8))) short bf16x8;
typedef __attribute__((ext_vector_type(4))) float f32x4;

__device__ __forceinline__ float4 h4_to_f4(uint2 u) {
  float2 fa = __half22float2(*(__half2*)&u.x);
  float2 fb = __half22float2(*(__half2*)&u.y);
  return make_float4(fa.x, fa.y, fb.x, fb.y);
}

__global__ __launch_bounds__(256) void k_zero_i32(int* __restrict__ p, int n) {
  int i = blockIdx.x * 256 + threadIdx.x;
  if (i < n) p[i] = 0;
}

// per-block LDS histogram of dst into buckets of BSZ nodes
__global__ __launch_bounds__(256) void k_bucket_hist(const int* __restrict__ dst,
                                                     int* __restrict__ gcnt,
                                                     int e, int kb) {
  __shared__ int h[128];
  int tid = threadIdx.x;
  if (tid < kb) h[tid] = 0;
  __syncthreads();
  int stride = gridDim.x * 256;
  for (int i = blockIdx.x * 256 + tid; i < e; i += stride) {
    int d = __builtin_nontemporal_load(&dst[i]);
    atomicAdd(&h[d >> BSH], 1);
  }
  __syncthreads();
  if (tid < kb) atomicAdd(&gcnt[tid], h[tid]);
}

// 1 block, 128 threads: exclusive scan of bucket counts -> gbase, gcur
__global__ __launch_bounds__(128) void k_bucket_scan(const int* __restrict__ gcnt,
                                                     int* __restrict__ gbase,
                                                     int* __restrict__ gcur,
                                                     int kb) {
  __shared__ int ws[2];
  int t = threadIdx.x;
  int lane = t & 63, w = t >> 6;
  int v = (t < kb) ? gcnt[t] : 0;
  int orig = v;
#pragma unroll
  for (int o = 1; o < 64; o <<= 1) {
    int u = __shfl_up(v, o, 64);
    if (lane >= o) v += u;
  }
  if (lane == 63) ws[w] = v;
  __syncthreads();
  int ex = ((w == 1) ? ws[0] : 0) + v - orig;
  if (t < kb) { gbase[t] = ex; gcur[t] = ex; }
  if (t == kb - 1) gbase[kb] = ex + orig;
}

// multisplit: one 4096-edge batch per block; per-edge intra-bucket rank from
// LDS histogram; one global atomic per bucket per batch reserves a contiguous
// segment; packed edge = (d_local << 16) | src   [valid: src < 65536]
__global__ __launch_bounds__(256) void k_multisplit(const int* __restrict__ src,
                                                    const int* __restrict__ dst,
                                                    int* __restrict__ gcur,
                                                    int* __restrict__ tmp,
                                                    int e, int kb) {
  __shared__ int h[128], base[128];
  int tid = threadIdx.x;
  if (tid < kb) h[tid] = 0;
  __syncthreads();
  int i0 = blockIdx.x * MSB + tid;
  int d[16], rk[16];
#pragma unroll
  for (int u = 0; u < 16; ++u) {
    int i = i0 + u * 256;
    if (i < e) {
      d[u] = __builtin_nontemporal_load(&dst[i]);
      rk[u] = atomicAdd(&h[d[u] >> BSH], 1);
    }
  }
  __syncthreads();
  if (tid < kb && h[tid] > 0) base[tid] = atomicAdd(&gcur[tid], h[tid]);
  __syncthreads();
#pragma unroll
  for (int u = 0; u < 16; ++u) {
    int i = i0 + u * 256;
    if (i < e) {
      int s = __builtin_nontemporal_load(&src[i]);
      tmp[base[d[u] >> BSH] + rk[u]] = ((d[u] & (BSZ - 1)) << 16) | s;
    }
  }
}

// one block per bucket: per-node degree + scan + cursor scatter, all in LDS.
// colarr written as u16 (src < 65536), bucket-local so no write-amp.
__global__ __launch_bounds__(512) void k_bucket_build(
    const int* __restrict__ tmp, const int* __restrict__ gbase,
    int* __restrict__ rowptr, float* __restrict__ dinv,
    unsigned short* __restrict__ colarr, int n, int kb, int e) {
  __shared__ int dl[BSZ], cl[BSZ], ws[8];
  int t = threadIdx.x, b = blockIdx.x;
  int s0 = gbase[b], s1 = gbase[b + 1];
  dl[t] = 0;
  __syncthreads();
  for (int j = s0 + t; j < s1; j += 512)
    atomicAdd(&dl[((unsigned)tmp[j]) >> 16], 1);
  __syncthreads();
  int lane = t & 63, w = t >> 6;
  int v = dl[t], orig = v;
#pragma unroll
  for (int o = 1; o < 64; o <<= 1) {
    int u = __shfl_up(v, o, 64);
    if (lane >= o) v += u;
  }
  if (lane == 63) ws[w] = v;
  __syncthreads();
  if (t == 0) {
    int a = 0;
#pragma unroll
    for (int k = 0; k < 8; ++k) { int x = ws[k]; ws[k] = a; a += x; }
  }
  __syncthreads();
  int ex = ws[w] + v - orig;
  cl[t] = ex;
  int node = (b << BSH) + t;
  if (node < n) {
    rowptr[node] = s0 + ex;
    dinv[node] = rsqrtf((float)(orig + 1));  // +1 self loop
  }
  if (b == kb - 1 && t == 0) rowptr[n] = e;
  __syncthreads();
  for (int j = s0 + t; j < s1; j += 512) {
    int p = tmp[j];
    int r = atomicAdd(&cl[((unsigned)p) >> 16], 1);
    colarr[s0 + r] = (unsigned short)(p & 0xFFFF);
  }
}

// --- MFMA GEMM machinery ----------------------------------------------------
// Exact split: x = hi(bf16, trunc) + lo(bf16, trunc) + O(2^-17 |x|).
__device__ __forceinline__ void split8(const float* v, bf16x8& hi, bf16x8& lo) {
#pragma unroll
  for (int j = 0; j < 8; ++j) {
    unsigned u = __float_as_uint(v[j]);
    hi[j] = (short)(u >> 16);
    float lf = v[j] - __uint_as_float(u & 0xffff0000u);
    lo[j] = (short)(__float_as_uint(lf) >> 16);
  }
}

// Precompute B-operand bf16 hi/lo fragments for the 4 weight matrices.
// Slot g = ((w*8 + t)*4 + s)*64 + lane ; lane holds B[k=s*32+quad*8+j][n=16t+(lane&15)]
__global__ __launch_bounds__(256) void k_prep_w(
    const float* __restrict__ W1, const float* __restrict__ W2,
    const float* __restrict__ Wh1, short* __restrict__ fragH,
    short* __restrict__ fragL) {
  int g = blockIdx.x * 256 + threadIdx.x;
  if (g >= 4 * 2048) return;
  int w = g >> 11;
  int rem = g & 2047;
  int lane = rem & 63;
  int ts = rem >> 6;          // t*4 + s
  int t = ts >> 2, s = ts & 3;
  int n = (t << 4) + (lane & 15);
  int k0 = s * 32 + (lane >> 4) * 8;
  const float* W = (w == 0) ? W1 : (w == 1) ? W2 : (w == 2) ? Wh1 : (Wh1 + 128 * 128);
  short h[8], l[8];
#pragma unroll
  for (int j = 0; j < 8; ++j) {
    float x = W[(k0 + j) * 128 + n];
    unsigned u = __float_as_uint(x);
    h[j] = (short)(u >> 16);
    float lf = x - __uint_as_float(u & 0xffff0000u);
    l[j] = (short)(__float_as_uint(lf) >> 16);
  }
  ((int4*)fragH)[g] = *(int4*)h;
  ((int4*)fragL)[g] = *(int4*)l;
}

// C16[n,128] = fp16( rowscale * (X[n,128] @ W) ) via 16x16x32 bf16 MFMA.
// Block = 64 rows (4 waves x 16). X-tile staged in LDS with coalesced
// float2 loads; fragments fed from LDS (stride 132 -> 2-way banks, free).
__global__ __launch_bounds__(256) void k_gemm_mfma(
    const float* __restrict__ X, const short* __restrict__ fragH,
    const short* __restrict__ fragL, const float* __restrict__ rowscale,
    __half* __restrict__ C16, int n) {
  __shared__ float sX[64 * XPAD];  // ~33.8 KB
  int tid = threadIdx.x;
  int row0 = blockIdx.x * 64;
  const float2* X2 = (const float2*)(X + (size_t)row0 * 128);
#pragma unroll
  for (int it = 0; it < 16; ++it) {
    int t = it * 256 + tid;           // 0..4095
    int r = t >> 6, c2 = t & 63;      // 64 float2 per row
    int gr = row0 + r;
    float2 v = (gr < n) ? X2[t] : make_float2(0.f, 0.f);
    *(float2*)&sX[r * XPAD + c2 * 2] = v;
  }
  __syncthreads();
  int wid = tid >> 6, lane = tid & 63;
  int r0 = row0 + wid * 16;
  if (r0 >= n) return;
  int m = lane & 15, quad = lane >> 4;
  const float* xrow = sX + (wid * 16 + m) * XPAD;
  f32x4 acc[8];
#pragma unroll
  for (int t = 0; t < 8; ++t) acc[t] = (f32x4)(0.f);
  const int4* FH = (const int4*)fragH;
  const int4* FL = (const int4*)fragL;
#pragma unroll
  for (int s = 0; s < 4; ++s) {
    int k0 = s * 32 + quad * 8;
    float xv[8];
    *(float2*)&xv[0] = *(const float2*)(xrow + k0);
    *(float2*)&xv[2] = *(const float2*)(xrow + k0 + 2);
    *(float2*)&xv[4] = *(const float2*)(xrow + k0 + 4);
    *(float2*)&xv[6] = *(const float2*)(xrow + k0 + 6);
    bf16x8 ah, al;
    split8(xv, ah, al);
#pragma unroll
    for (int t = 0; t < 8; ++t) {
      int idx = (t * 4 + s) * 64 + lane;
      bf16x8 bh = *(const bf16x8*)&FH[idx];
      bf16x8 bl = *(const bf16x8*)&FL[idx];
      acc[t] = __builtin_amdgcn_mfma_f32_16x16x32_bf16(ah, bh, acc[t], 0, 0, 0);
      acc[t] = __builtin_amdgcn_mfma_f32_16x16x32_bf16(al, bh, acc[t], 0, 0, 0);
      acc[t] = __builtin_amdgcn_mfma_f32_16x16x32_bf16(ah, bl, acc[t], 0, 0, 0);
    }
  }
  // C/D layout: col = lane&15, row = quad*4 + reg   [m89-verified mapping]
  float sc[4];
#pragma unroll
  for (int r = 0; r < 4; ++r)
    sc[r] = rowscale ? rowscale[r0 + quad * 4 + r] : 1.f;
#pragma unroll
  for (int t = 0; t < 8; ++t) {
#pragma unroll
    for (int r = 0; r < 4; ++r) {
      int row = r0 + quad * 4 + r;
      C16[(size_t)row * 128 + t * 16 + m] = __float2half(acc[t][r] * sc[r]);
    }
  }
}

// Dual-output GEMM for the head: A16 = X@Wa, B16 = X@Wb (no rowscale).
// Reads the X tile once for both outputs.
__global__ __launch_bounds__(256) void k_gemm_dual(
    const float* __restrict__ X,
    const short* __restrict__ fHa, const short* __restrict__ fLa,
    const short* __restrict__ fHb, const short* __restrict__ fLb,
    __half* __restrict__ A16, __half* __restrict__ B16, int n) {
  __shared__ float sX[64 * XPAD];
  int tid = threadIdx.x;
  int row0 = blockIdx.x * 64;
  const float2* X2 = (const float2*)(X + (size_t)row0 * 128);
#pragma unroll
  for (int it = 0; it < 16; ++it) {
    int t = it * 256 + tid;
    int r = t >> 6, c2 = t & 63;
    int gr = row0 + r;
    float2 v = (gr < n) ? X2[t] : make_float2(0.f, 0.f);
    *(float2*)&sX[r * XPAD + c2 * 2] = v;
  }
  __syncthreads();
  int wid = tid >> 6, lane = tid & 63;
  int r0 = row0 + wid * 16;
  if (r0 >= n) return;
  int m = lane & 15, quad = lane >> 4;
  const float* xrow = sX + (wid * 16 + m) * XPAD;
  f32x4 accA[8], accB[8];
#pragma unroll
  for (int t = 0; t < 8; ++t) { accA[t] = (f32x4)(0.f); accB[t] = (f32x4)(0.f); }
  const int4* FHa = (const int4*)fHa; const int4* FLa = (const int4*)fLa;
  const int4* FHb = (const int4*)fHb; const int4* FLb = (const int4*)fLb;
#pragma unroll
  for (int s = 0; s < 4; ++s) {
    int k0 = s * 32 + quad * 8;
    float xv[8];
    *(float2*)&xv[0] = *(const float2*)(xrow + k0);
    *(float2*)&xv[2] = *(const float2*)(xrow + k0 + 2);
    *(float2*)&xv[4] = *(const float2*)(xrow + k0 + 4);
    *(float2*)&xv[6] = *(const float2*)(xrow + k0 + 6);
    bf16x8 ah, al;
    split8(xv, ah, al);
#pragma unroll
    for (int t = 0; t < 8; ++t) {
      int idx = (t * 4 + s) * 64 + lane;
      bf16x8 bha = *(const bf16x8*)&FHa[idx];
      bf16x8 bla = *(const bf16x8*)&FLa[idx];
      accA[t] = __builtin_amdgcn_mfma_f32_16x16x32_bf16(ah, bha, accA[t], 0, 0, 0);
      accA[t] = __builtin_amdgcn_mfma_f32_16x16x32_bf16(al, bha, accA[t], 0, 0, 0);
      accA[t] = __builtin_amdgcn_mfma_f32_16x16x32_bf16(ah, bla, accA[t], 0, 0, 0);
      bf16x8 bhb = *(const bf16x8*)&FHb[idx];
      bf16x8 blb = *(const bf16x8*)&FLb[idx];
      accB[t] = __builtin_amdgcn_mfma_f32_16x16x32_bf16(ah, bhb, accB[t], 0, 0, 0);
      accB[t] = __builtin_amdgcn_mfma_f32_16x16x32_bf16(al, bhb, accB[t], 0, 0, 0);
      accB[t] = __builtin_amdgcn_mfma_f32_16x16x32_bf16(ah, blb, accB[t], 0, 0, 0);
    }
  }
#pragma unroll
  for (int t = 0; t < 8; ++t) {
#pragma unroll
    for (int r = 0; r < 4; ++r) {
      int row = r0 + quad * 4 + r;
      A16[(size_t)row * 128 + t * 16 + m] = __float2half(accA[t][r]);
      B16[(size_t)row * 128 + t * 16 + m] = __float2half(accB[t][r]);
    }
  }
}

// out[i,:] = relu(dinv[i] * (g[i,:] + sum_{e in row i} g[col[e],:]) + bias)
// half4 gather lanes: 32 lanes (8B each) cover one 256B row; wave = 2 edge
// subgroups -> 512B per wave-load, 8 edges in flight (4 slots x 2 subs).
__global__ __launch_bounds__(256) void k_agg_h(
    const __half2* __restrict__ g2, const float* __restrict__ dinv,
    const int* __restrict__ rowptr, const unsigned short* __restrict__ col,
    const float* __restrict__ bias, float* __restrict__ out, int n) {
  int i = blockIdx.x * 4 + (threadIdx.x >> 6);
  if (i >= n) return;
  int lane = threadIdx.x & 63;
  int sub = lane >> 5;   // edge subgroup 0/1
  int c4 = lane & 31;    // half4 column index (32 per row)
  const uint2* G4 = (const uint2*)g2;
  float4 a0 = make_float4(0.f, 0.f, 0.f, 0.f), a1 = a0, a2 = a0, a3 = a0;
  if (sub == 0) a0 = h4_to_f4(G4[(size_t)i * 32 + c4]);  // self loop once
  int beg = rowptr[i], end = rowptr[i + 1];
  int j = beg;
  for (; j + 8 <= end; j += 8) {
    int s0 = __builtin_nontemporal_load(&col[j + 0 + sub]);
    int s1 = __builtin_nontemporal_load(&col[j + 2 + sub]);
    int s2 = __builtin_nontemporal_load(&col[j + 4 + sub]);
    int s3 = __builtin_nontemporal_load(&col[j + 6 + sub]);
    float4 v0 = h4_to_f4(G4[(size_t)s0 * 32 + c4]);
    float4 v1 = h4_to_f4(G4[(size_t)s1 * 32 + c4]);
    float4 v2 = h4_to_f4(G4[(size_t)s2 * 32 + c4]);
    float4 v3 = h4_to_f4(G4[(size_t)s3 * 32 + c4]);
    a0.x += v0.x; a0.y += v0.y; a0.z += v0.z; a0.w += v0.w;
    a1.x += v1.x; a1.y += v1.y; a1.z += v1.z; a1.w += v1.w;
    a2.x += v2.x; a2.y += v2.y; a2.z += v2.z; a2.w += v2.w;
    a3.x += v3.x; a3.y += v3.y; a3.z += v3.z; a3.w += v3.w;
  }
  for (; j + 2 <= end; j += 2) {
    int s0 = __builtin_nontemporal_load(&col[j + sub]);
    float4 v = h4_to_f4(G4[(size_t)s0 * 32 + c4]);
    a0.x += v.x; a0.y += v.y; a0.z += v.z; a0.w += v.w;
  }
  if (j < end && sub == 0) {
    int s0 = __builtin_nontemporal_load(&col[j]);
    float4 v = h4_to_f4(G4[(size_t)s0 * 32 + c4]);
    a0.x += v.x; a0.y += v.y; a0.z += v.z; a0.w += v.w;
  }
  float4 s;
  s.x = (a0.x + a1.x) + (a2.x + a3.x);
  s.y = (a0.y + a1.y) + (a2.y + a3.y);
  s.z = (a0.z + a1.z) + (a2.z + a3.z);
  s.w = (a0.w + a1.w) + (a2.w + a3.w);
  s.x += __shfl_down(s.x, 32, 64);
  s.y += __shfl_down(s.y, 32, 64);
  s.z += __shfl_down(s.z, 32, 64);
  s.w += __shfl_down(s.w, 32, 64);
  if (sub == 0) {
    float di = dinv[i];
    float4 bi = ((const float4*)bias)[c4];
    float4 o;
    o.x = fmaxf(fmaf(di, s.x, bi.x), 0.f);
    o.y = fmaxf(fmaf(di, s.y, bi.y), 0.f);
    o.z = fmaxf(fmaf(di, s.z, bi.z), 0.f);
    o.w = fmaxf(fmaf(di, s.w, bi.w), 0.f);
    ((float4*)out)[(size_t)i * 32 + c4] = o;
  }
}

// one wave per pair: sub0 loads A[p0] half4, sub1 loads B[p1] half4;
// combine via shfl_xor(32), dot with wh2, reduce over 32 lanes.
__global__ __launch_bounds__(256) void k_pairs_h(
    const __half2* __restrict__ A, const __half2* __restrict__ B,
    const int* __restrict__ pairs, const float* __restrict__ bh1,
    const float* __restrict__ wh2, const float* __restrict__ bh2,
    float* __restrict__ out, int P) {
  int p = blockIdx.x * 4 + (threadIdx.x >> 6);
  int lane = threadIdx.x & 63;
  if (p >= P) return;
  int sub = lane >> 5, c4 = lane & 31;
  int p0 = pairs[2 * p], p1 = pairs[2 * p + 1];
  const uint2* T4 = sub ? (const uint2*)B : (const uint2*)A;
  int row = sub ? p1 : p0;
  float4 v = h4_to_f4(T4[(size_t)row * 32 + c4]);
  v.x += __shfl_xor(v.x, 32, 64);
  v.y += __shfl_xor(v.y, 32, 64);
  v.z += __shfl_xor(v.z, 32, 64);
  v.w += __shfl_xor(v.w, 32, 64);
  float4 bi = ((const float4*)bh1)[c4];
  float4 wv = ((const float4*)wh2)[c4];
  float s = fmaxf(v.x + bi.x, 0.f) * wv.x + fmaxf(v.y + bi.y, 0.f) * wv.y +
            fmaxf(v.z + bi.z, 0.f) * wv.z + fmaxf(v.w + bi.w, 0.f) * wv.w;
#pragma unroll
  for (int o = 16; o > 0; o >>= 1) s += __shfl_down(s, o, 64);
  if (lane == 0) out[p] = s + bh2[0];
}

extern "C" void kernel_launch(void* const* d_in, const int* in_sizes, int n_in,
                              void* d_out, int out_size, void* d_ws, size_t ws_size,
                              hipStream_t stream) {
  const float* x   = (const float*)d_in[0];
  const int* ei    = (const int*)d_in[1];
  const int* pairs = (const int*)d_in[2];
  const float* W1  = (const float*)d_in[3];
  const float* b1  = (const float*)d_in[4];
  const float* W2  = (const float*)d_in[5];
  const float* b2  = (const float*)d_in[6];
  const float* Wh1 = (const float*)d_in[7];
  const float* bh1 = (const float*)d_in[8];
  const float* Wh2 = (const float*)d_in[9];
  const float* bh2 = (const float*)d_in[10];
  (void)n_in; (void)out_size; (void)ws_size;

  int N = in_sizes[0] / 128;
  int E = in_sizes[1] / 2;
  int P = in_sizes[2] / 2;
  const int* src = ei;
  const int* dst = ei + E;
  int KB = (N + BSZ - 1) >> BSH;  // buckets (98 for N=50000)

  char* wsp = (char*)d_ws;
  size_t off = 0;
  auto alloc = [&](size_t bytes) -> void* {
    void* p = wsp + off;
    off += (bytes + 255) & ~(size_t)255;
    return p;
  };
  __half* g16 = (__half*)alloc((size_t)N * 128 * 2);  // messages; reused as A16
  float* h1   = (float*)alloc((size_t)N * 128 * 4);   // reused as B16 (fp16)
  float* h2   = (float*)alloc((size_t)N * 128 * 4);
  float* dinv = (float*)alloc((size_t)N * 4);
  int* rowptr = (int*)alloc((size_t)(N + 1) * 4);
  unsigned short* colarr = (unsigned short*)alloc((size_t)E * 2);
  int* tmp    = (int*)alloc((size_t)E * 4);           // packed bucketed edges
  short* fragH = (short*)alloc(4 * 2048 * 8 * 2);     // 128KB
  short* fragL = (short*)alloc(4 * 2048 * 8 * 2);     // 128KB
  int* gcnt  = (int*)alloc((size_t)(KB + 1) * 4);
  int* gbase = (int*)alloc((size_t)(KB + 1) * 4);
  int* gcur  = (int*)alloc((size_t)(KB + 1) * 4);
  __half* A16 = g16;            // g16 dead by the time head runs
  __half* B16 = (__half*)h1;    // h1 dead after conv2 gemm
  // per-W frag bases (2048 slots * 8 shorts each)
  short* fH_W1 = fragH + 0 * 16384;  short* fL_W1 = fragL + 0 * 16384;
  short* fH_W2 = fragH + 1 * 16384;  short* fL_W2 = fragL + 1 * 16384;
  short* fH_Wa = fragH + 2 * 16384;  short* fL_Wa = fragL + 2 * 16384;
  short* fH_Wb = fragH + 3 * 16384;  short* fL_Wb = fragL + 3 * 16384;

  // weight fragment prep (independent of CSR)
  k_prep_w<<<32, 256, 0, stream>>>(W1, W2, Wh1, fragH, fragL);

  // CSR build: hist -> scan -> multisplit -> per-bucket LDS sort
  k_zero_i32<<<1, 256, 0, stream>>>(gcnt, KB + 1);
  k_bucket_hist<<<256, 256, 0, stream>>>(dst, gcnt, E, KB);
  k_bucket_scan<<<1, 128, 0, stream>>>(gcnt, gbase, gcur, KB);
  k_multisplit<<<(E + MSB - 1) / MSB, 256, 0, stream>>>(src, dst, gcur, tmp, E, KB);
  k_bucket_build<<<KB, 512, 0, stream>>>(tmp, gbase, rowptr, dinv, colarr, N, KB, E);

  int GB = (N + 63) / 64;          // gemm: 64 rows per block
  int AB = (N + 3) / 4;            // agg: 4 rows per block
  // conv1
  k_gemm_mfma<<<GB, 256, 0, stream>>>(x, fH_W1, fL_W1, dinv, g16, N);
  k_agg_h<<<AB, 256, 0, stream>>>((const __half2*)g16, dinv, rowptr, colarr, b1, h1, N);
  // conv2
  k_gemm_mfma<<<GB, 256, 0, stream>>>(h1, fH_W2, fL_W2, dinv, g16, N);
  k_agg_h<<<AB, 256, 0, stream>>>((const __half2*)g16, dinv, rowptr, colarr, b2, h2, N);
  // head: A = h2 @ Wh1_top, B = h2 @ Wh1_bot (fused, reads h2 once)
  k_gemm_dual<<<GB, 256, 0, stream>>>(h2, fH_Wa, fL_Wa, fH_Wb, fL_Wb, A16, B16, N);
  k_pairs_h<<<(P + 3) / 4, 256, 0, stream>>>((const __half2*)A16, (const __half2*)B16,
                                             pairs, bh1, Wh2, bh2, (float*)d_out, P);
}

// Round 12
// 377.159 us; speedup vs baseline: 1.5013x; 1.0222x over previous
//
#include <hip/hip_runtime.h>
#include <hip/hip_fp16.h>

// ---------------------------------------------------------------------------
// LinkPredictionGNN: 2x GCNConv (self-loops, sym-norm) + pair MLP head.
//   K1 prep_w (+zero gcnt/gcur)   K2 hist   K3 multisplit   K4 bucket_build
//   K5 gemm1   K6 agg1   K7 gemm2   K8 agg2   K9 gemm_dual   K10 pairs
//
// R1/R4: random 4B global writes/atomics -> ~10x line-writeback amp; spatial
//   XCD-affinity tricks regress. R6/R7: column-slicing the gather fails too;
//   XCD L2 locality is not schedulable from HIP.
// R5: CSR build = 2-level bucket sort, zero global random atomics.
// R8: gemm X-tile staged via coalesced float2->LDS (stride 132).
// R9: agg half4 lanes (8 edges in flight) -> 62us.
// R10 FAILED: fusing gemm1 into the hist dispatch broke ordering — gemm1
//   reads dinv, which bucket_build (K4) writes. GEMM1 must follow the CSR
//   build. Kept: uint4 agg lanes (16 edges in flight), multisplit per-wave
//   replicated LDS hist + in-block scans, zeroing folded into prep_w.
// R2: fp16 message/A/B tables (absmax 4.9e-4 < 1.5e-3 threshold).
// R3: double-bf16-split MFMA GEMM (Ah.Bh+Al.Bh+Ah.Bl).
// ---------------------------------------------------------------------------

#define BSH 9                 // log2 nodes per bucket
#define BSZ (1 << BSH)        // 512 nodes per bucket
#define MSB 4096              // edges per multisplit batch/block
#define XPAD 132              // LDS row stride (floats): 8B-aligned, 2-way banks
#define HB 256                // hist blocks

typedef __attribute__((ext_vector_type(8))) short bf16x8;
typedef __attribute__((ext_vector_type(4))) float f32x4;

__device__ __forceinline__ void acc8(uint4 u, float4& lo, float4& hi) {
  float2 f0 = __half22float2(((const __half2*)&u)[0]);
  float2 f1 = __half22float2(((const __half2*)&u)[1]);
  float2 f2 = __half22float2(((const __half2*)&u)[2]);
  float2 f3 = __half22float2(((const __half2*)&u)[3]);
  lo.x += f0.x; lo.y += f0.y; lo.z += f1.x; lo.w += f1.y;
  hi.x += f2.x; hi.y += f2.y; hi.z += f3.x; hi.w += f3.y;
}

__device__ __forceinline__ float4 h4_to_f4(uint2 u) {
  float2 fa = __half22float2(*(__half2*)&u.x);
  float2 fb = __half22float2(*(__half2*)&u.y);
  return make_float4(fa.x, fa.y, fb.x, fb.y);
}

// --- MFMA GEMM machinery ----------------------------------------------------
// Exact split: x = hi(bf16, trunc) + lo(bf16, trunc) + O(2^-17 |x|).
__device__ __forceinline__ void split8(const float* v, bf16x8& hi, bf16x8& lo) {
#pragma unroll
  for (int j = 0; j < 8; ++j) {
    unsigned u = __float_as_uint(v[j]);
    hi[j] = (short)(u >> 16);
    float lf = v[j] - __uint_as_float(u & 0xffff0000u);
    lo[j] = (short)(__float_as_uint(lf) >> 16);
  }
}

// Precompute B-operand bf16 hi/lo fragments for the 4 weight matrices.
// Block 32 zeroes gcnt/gcur (hist runs in the NEXT dispatch -> safe).
__global__ __launch_bounds__(256) void k_prep_w(
    const float* __restrict__ W1, const float* __restrict__ W2,
    const float* __restrict__ Wh1, short* __restrict__ fragH,
    short* __restrict__ fragL, int* __restrict__ gcnt, int* __restrict__ gcur,
    int kb) {
  if (blockIdx.x == 32) {
    int t = threadIdx.x;
    if (t < kb) { gcnt[t] = 0; gcur[t] = 0; }
    return;
  }
  int g = blockIdx.x * 256 + threadIdx.x;
  int w = g >> 11;
  int rem = g & 2047;
  int lane = rem & 63;
  int ts = rem >> 6;          // t*4 + s
  int t = ts >> 2, s = ts & 3;
  int n = (t << 4) + (lane & 15);
  int k0 = s * 32 + (lane >> 4) * 8;
  const float* W = (w == 0) ? W1 : (w == 1) ? W2 : (w == 2) ? Wh1 : (Wh1 + 128 * 128);
  short h[8], l[8];
#pragma unroll
  for (int j = 0; j < 8; ++j) {
    float x = W[(k0 + j) * 128 + n];
    unsigned u = __float_as_uint(x);
    h[j] = (short)(u >> 16);
    float lf = x - __uint_as_float(u & 0xffff0000u);
    l[j] = (short)(__float_as_uint(lf) >> 16);
  }
  ((int4*)fragH)[g] = *(int4*)h;
  ((int4*)fragL)[g] = *(int4*)l;
}

// bucket histogram of dst, per-wave replicated LDS counters.
__global__ __launch_bounds__(256) void k_hist(const int* __restrict__ dst,
                                              int* __restrict__ gcnt,
                                              int e, int kb) {
  __shared__ int h4[512];
  int tid = threadIdx.x, wid = tid >> 6;
  for (int t = tid; t < 512; t += 256) h4[t] = 0;
  __syncthreads();
  for (int i = blockIdx.x * 256 + tid; i < e; i += HB * 256) {
    int d = __builtin_nontemporal_load(&dst[i]);
    atomicAdd(&h4[wid * 128 + (d >> BSH)], 1);
  }
  __syncthreads();
  if (tid < kb)
    atomicAdd(&gcnt[tid], h4[tid] + h4[128 + tid] + h4[256 + tid] + h4[384 + tid]);
}

// gemm body: C16[64 rows] = fp16(rowscale * X@W), X-tile staged in LDS.
__device__ __forceinline__ void gemm_body(
    const float* __restrict__ X, const short* __restrict__ fragH,
    const short* __restrict__ fragL, const float* __restrict__ rowscale,
    __half* __restrict__ C16, int n, int bid, float* sX) {
  int tid = threadIdx.x;
  int row0 = bid * 64;
  const float2* X2 = (const float2*)(X + (size_t)row0 * 128);
#pragma unroll
  for (int it = 0; it < 16; ++it) {
    int t = it * 256 + tid;           // 0..4095
    int r = t >> 6, c2 = t & 63;
    int gr = row0 + r;
    float2 v = (gr < n) ? X2[t] : make_float2(0.f, 0.f);
    *(float2*)&sX[r * XPAD + c2 * 2] = v;
  }
  __syncthreads();
  int wid = tid >> 6, lane = tid & 63;
  int r0 = row0 + wid * 16;
  if (r0 >= n) return;
  int m = lane & 15, quad = lane >> 4;
  const float* xrow = sX + (wid * 16 + m) * XPAD;
  f32x4 acc[8];
#pragma unroll
  for (int t = 0; t < 8; ++t) acc[t] = (f32x4)(0.f);
  const int4* FH = (const int4*)fragH;
  const int4* FL = (const int4*)fragL;
#pragma unroll
  for (int s = 0; s < 4; ++s) {
    int k0 = s * 32 + quad * 8;
    float xv[8];
    *(float2*)&xv[0] = *(const float2*)(xrow + k0);
    *(float2*)&xv[2] = *(const float2*)(xrow + k0 + 2);
    *(float2*)&xv[4] = *(const float2*)(xrow + k0 + 4);
    *(float2*)&xv[6] = *(const float2*)(xrow + k0 + 6);
    bf16x8 ah, al;
    split8(xv, ah, al);
#pragma unroll
    for (int t = 0; t < 8; ++t) {
      int idx = (t * 4 + s) * 64 + lane;
      bf16x8 bh = *(const bf16x8*)&FH[idx];
      bf16x8 bl = *(const bf16x8*)&FL[idx];
      acc[t] = __builtin_amdgcn_mfma_f32_16x16x32_bf16(ah, bh, acc[t], 0, 0, 0);
      acc[t] = __builtin_amdgcn_mfma_f32_16x16x32_bf16(al, bh, acc[t], 0, 0, 0);
      acc[t] = __builtin_amdgcn_mfma_f32_16x16x32_bf16(ah, bl, acc[t], 0, 0, 0);
    }
  }
  // C/D layout: col = lane&15, row = quad*4 + reg   [m89-verified mapping]
  float sc[4];
#pragma unroll
  for (int r = 0; r < 4; ++r)
    sc[r] = rowscale ? rowscale[r0 + quad * 4 + r] : 1.f;
#pragma unroll
  for (int t = 0; t < 8; ++t) {
#pragma unroll
    for (int r = 0; r < 4; ++r) {
      int row = r0 + quad * 4 + r;
      C16[(size_t)row * 128 + t * 16 + m] = __float2half(acc[t][r] * sc[r]);
    }
  }
}

__global__ __launch_bounds__(256) void k_gemm_mfma(
    const float* __restrict__ X, const short* __restrict__ fragH,
    const short* __restrict__ fragL, const float* __restrict__ rowscale,
    __half* __restrict__ C16, int n) {
  __shared__ float sX[64 * XPAD];
  gemm_body(X, fragH, fragL, rowscale, C16, n, blockIdx.x, sX);
}

// multisplit: per-wave replicated LDS hist for ranks; in-block exclusive scan
// of gcnt gives global bucket bases; one global atomic per bucket per batch
// reserves a contiguous segment. packed = (d_local<<16)|src  [src < 65536]
__global__ __launch_bounds__(256) void k_multisplit(const int* __restrict__ src,
                                                    const int* __restrict__ dst,
                                                    const int* __restrict__ gcnt,
                                                    int* __restrict__ gcur,
                                                    int* __restrict__ tmp,
                                                    int e, int kb) {
  __shared__ int h4[4 * 128], off[4 * 128], sbase[128], ws[2];
  int tid = threadIdx.x, wid = tid >> 6, lane = tid & 63;
  for (int t = tid; t < 512; t += 256) h4[t] = 0;
  __syncthreads();
  int i0 = blockIdx.x * MSB + tid;
  int d[16], rk[16];
#pragma unroll
  for (int u = 0; u < 16; ++u) {
    int i = i0 + u * 256;
    if (i < e) {
      d[u] = __builtin_nontemporal_load(&dst[i]);
      rk[u] = atomicAdd(&h4[wid * 128 + (d[u] >> BSH)], 1);
    }
  }
  __syncthreads();
  int tot = 0;
  if (tid < 128) {
    int c0 = h4[tid], c1 = h4[128 + tid], c2 = h4[256 + tid], c3 = h4[384 + tid];
    off[tid] = 0; off[128 + tid] = c0;
    off[256 + tid] = c0 + c1; off[384 + tid] = c0 + c1 + c2;
    tot = c0 + c1 + c2 + c3;
  }
  // exclusive scan of gcnt (threads 0..127)
  int v = (tid < 128 && tid < kb) ? gcnt[tid] : 0;
  int orig = v;
#pragma unroll
  for (int o = 1; o < 64; o <<= 1) {
    int u = __shfl_up(v, o, 64);
    if (lane >= o) v += u;
  }
  if (lane == 63 && wid < 2) ws[wid] = v;
  __syncthreads();
  if (tid < 128) sbase[tid] = ((wid == 1) ? ws[0] : 0) + v - orig;
  __syncthreads();
  if (tid < kb && tot > 0) sbase[tid] += atomicAdd(&gcur[tid], tot);
  __syncthreads();
#pragma unroll
  for (int u = 0; u < 16; ++u) {
    int i = i0 + u * 256;
    if (i < e) {
      int s = __builtin_nontemporal_load(&src[i]);
      int k = d[u] >> BSH;
      tmp[sbase[k] + off[wid * 128 + k] + rk[u]] = ((d[u] & (BSZ - 1)) << 16) | s;
    }
  }
}

// one block per bucket: in-block scan of gcnt for bases; per-node degree +
// scan + cursor scatter, all in LDS. colarr u16, bucket-local (no write-amp).
__global__ __launch_bounds__(512) void k_bucket_build(
    const int* __restrict__ tmp, const int* __restrict__ gcnt,
    int* __restrict__ rowptr, float* __restrict__ dinv,
    unsigned short* __restrict__ colarr, int n, int kb, int e) {
  __shared__ int dl[BSZ], cl[BSZ], sbase[128], ws[8];
  int t = threadIdx.x, b = blockIdx.x;
  int lane = t & 63, w = t >> 6;
  // exclusive scan of gcnt (threads 0..127)
  int v = (t < 128 && t < kb) ? gcnt[t] : 0;
  int orig0 = v;
#pragma unroll
  for (int o = 1; o < 64; o <<= 1) {
    int u = __shfl_up(v, o, 64);
    if (lane >= o) v += u;
  }
  if (lane == 63 && w < 2) ws[w] = v;
  dl[t] = 0;
  __syncthreads();
  if (t < 128) sbase[t] = ((w == 1) ? ws[0] : 0) + v - orig0;
  __syncthreads();
  int s0 = sbase[b];
  int s1 = s0 + gcnt[b];
  for (int j = s0 + t; j < s1; j += 512)
    atomicAdd(&dl[((unsigned)tmp[j]) >> 16], 1);
  __syncthreads();
  int dv = dl[t], orig = dv;
#pragma unroll
  for (int o = 1; o < 64; o <<= 1) {
    int u = __shfl_up(dv, o, 64);
    if (lane >= o) dv += u;
  }
  if (lane == 63) ws[w] = dv;
  __syncthreads();
  if (t == 0) {
    int a = 0;
#pragma unroll
    for (int k = 0; k < 8; ++k) { int x = ws[k]; ws[k] = a; a += x; }
  }
  __syncthreads();
  int ex = ws[w] + dv - orig;
  cl[t] = ex;
  int node = (b << BSH) + t;
  if (node < n) {
    rowptr[node] = s0 + ex;
    dinv[node] = rsqrtf((float)(orig + 1));  // +1 self loop
  }
  if (b == kb - 1 && t == 0) rowptr[n] = e;
  __syncthreads();
  for (int j = s0 + t; j < s1; j += 512) {
    int p = tmp[j];
    int r = atomicAdd(&cl[((unsigned)p) >> 16], 1);
    colarr[s0 + r] = (unsigned short)(p & 0xFFFF);
  }
}

// Dual-output GEMM for the head: A16 = X@Wa, B16 = X@Wb (reads X once).
__global__ __launch_bounds__(256) void k_gemm_dual(
    const float* __restrict__ X,
    const short* __restrict__ fHa, const short* __restrict__ fLa,
    const short* __restrict__ fHb, const short* __restrict__ fLb,
    __half* __restrict__ A16, __half* __restrict__ B16, int n) {
  __shared__ float sX[64 * XPAD];
  int tid = threadIdx.x;
  int row0 = blockIdx.x * 64;
  const float2* X2 = (const float2*)(X + (size_t)row0 * 128);
#pragma unroll
  for (int it = 0; it < 16; ++it) {
    int t = it * 256 + tid;
    int r = t >> 6, c2 = t & 63;
    int gr = row0 + r;
    float2 v = (gr < n) ? X2[t] : make_float2(0.f, 0.f);
    *(float2*)&sX[r * XPAD + c2 * 2] = v;
  }
  __syncthreads();
  int wid = tid >> 6, lane = tid & 63;
  int r0 = row0 + wid * 16;
  if (r0 >= n) return;
  int m = lane & 15, quad = lane >> 4;
  const float* xrow = sX + (wid * 16 + m) * XPAD;
  f32x4 accA[8], accB[8];
#pragma unroll
  for (int t = 0; t < 8; ++t) { accA[t] = (f32x4)(0.f); accB[t] = (f32x4)(0.f); }
  const int4* FHa = (const int4*)fHa; const int4* FLa = (const int4*)fLa;
  const int4* FHb = (const int4*)fHb; const int4* FLb = (const int4*)fLb;
#pragma unroll
  for (int s = 0; s < 4; ++s) {
    int k0 = s * 32 + quad * 8;
    float xv[8];
    *(float2*)&xv[0] = *(const float2*)(xrow + k0);
    *(float2*)&xv[2] = *(const float2*)(xrow + k0 + 2);
    *(float2*)&xv[4] = *(const float2*)(xrow + k0 + 4);
    *(float2*)&xv[6] = *(const float2*)(xrow + k0 + 6);
    bf16x8 ah, al;
    split8(xv, ah, al);
#pragma unroll
    for (int t = 0; t < 8; ++t) {
      int idx = (t * 4 + s) * 64 + lane;
      bf16x8 bha = *(const bf16x8*)&FHa[idx];
      bf16x8 bla = *(const bf16x8*)&FLa[idx];
      accA[t] = __builtin_amdgcn_mfma_f32_16x16x32_bf16(ah, bha, accA[t], 0, 0, 0);
      accA[t] = __builtin_amdgcn_mfma_f32_16x16x32_bf16(al, bha, accA[t], 0, 0, 0);
      accA[t] = __builtin_amdgcn_mfma_f32_16x16x32_bf16(ah, bla, accA[t], 0, 0, 0);
      bf16x8 bhb = *(const bf16x8*)&FHb[idx];
      bf16x8 blb = *(const bf16x8*)&FLb[idx];
      accB[t] = __builtin_amdgcn_mfma_f32_16x16x32_bf16(ah, bhb, accB[t], 0, 0, 0);
      accB[t] = __builtin_amdgcn_mfma_f32_16x16x32_bf16(al, bhb, accB[t], 0, 0, 0);
      accB[t] = __builtin_amdgcn_mfma_f32_16x16x32_bf16(ah, blb, accB[t], 0, 0, 0);
    }
  }
#pragma unroll
  for (int t = 0; t < 8; ++t) {
#pragma unroll
    for (int r = 0; r < 4; ++r) {
      int row = r0 + quad * 4 + r;
      A16[(size_t)row * 128 + t * 16 + m] = __float2half(accA[t][r]);
      B16[(size_t)row * 128 + t * 16 + m] = __float2half(accB[t][r]);
    }
  }
}

// out[i,:] = relu(dinv[i] * (g[i,:] + sum_{e in row i} g[col[e],:]) + bias)
// uint4 gather lanes: 16 lanes (16B) cover one 256B row; wave = 4 edge
// subgroups -> 1KB per wave-load instr; 4-deep unroll = 16 edges in flight.
__global__ __launch_bounds__(256) void k_agg_h(
    const __half2* __restrict__ g2, const float* __restrict__ dinv,
    const int* __restrict__ rowptr, const unsigned short* __restrict__ col,
    const float* __restrict__ bias, float* __restrict__ out, int n) {
  int i = blockIdx.x * 4 + (threadIdx.x >> 6);
  if (i >= n) return;
  int lane = threadIdx.x & 63;
  int sub = lane >> 4;   // edge subgroup 0..3
  int c8 = lane & 15;    // uint4 column (16 per row)
  const uint4* G = (const uint4*)g2;
  float4 z = make_float4(0.f, 0.f, 0.f, 0.f);
  float4 lo0 = z, lo1 = z, lo2 = z, lo3 = z, hi0 = z, hi1 = z, hi2 = z, hi3 = z;
  if (sub == 0) acc8(G[(size_t)i * 16 + c8], lo0, hi0);  // self loop once
  int beg = rowptr[i], end = rowptr[i + 1];
  int j = beg;
  for (; j + 16 <= end; j += 16) {
    int s0 = __builtin_nontemporal_load(&col[j + sub]);
    int s1 = __builtin_nontemporal_load(&col[j + 4 + sub]);
    int s2 = __builtin_nontemporal_load(&col[j + 8 + sub]);
    int s3 = __builtin_nontemporal_load(&col[j + 12 + sub]);
    uint4 u0 = G[(size_t)s0 * 16 + c8];
    uint4 u1 = G[(size_t)s1 * 16 + c8];
    uint4 u2 = G[(size_t)s2 * 16 + c8];
    uint4 u3 = G[(size_t)s3 * 16 + c8];
    acc8(u0, lo0, hi0); acc8(u1, lo1, hi1);
    acc8(u2, lo2, hi2); acc8(u3, lo3, hi3);
  }
  for (; j + 4 <= end; j += 4) {
    int s0 = __builtin_nontemporal_load(&col[j + sub]);
    acc8(G[(size_t)s0 * 16 + c8], lo1, hi1);
  }
  int rem = end - j;
  if (sub < rem) {
    int s0 = __builtin_nontemporal_load(&col[j + sub]);
    acc8(G[(size_t)s0 * 16 + c8], lo2, hi2);
  }
  float4 lo, hi;
  lo.x = (lo0.x + lo1.x) + (lo2.x + lo3.x);
  lo.y = (lo0.y + lo1.y) + (lo2.y + lo3.y);
  lo.z = (lo0.z + lo1.z) + (lo2.z + lo3.z);
  lo.w = (lo0.w + lo1.w) + (lo2.w + lo3.w);
  hi.x = (hi0.x + hi1.x) + (hi2.x + hi3.x);
  hi.y = (hi0.y + hi1.y) + (hi2.y + hi3.y);
  hi.z = (hi0.z + hi1.z) + (hi2.z + hi3.z);
  hi.w = (hi0.w + hi1.w) + (hi2.w + hi3.w);
  lo.x += __shfl_down(lo.x, 32, 64); lo.x += __shfl_down(lo.x, 16, 64);
  lo.y += __shfl_down(lo.y, 32, 64); lo.y += __shfl_down(lo.y, 16, 64);
  lo.z += __shfl_down(lo.z, 32, 64); lo.z += __shfl_down(lo.z, 16, 64);
  lo.w += __shfl_down(lo.w, 32, 64); lo.w += __shfl_down(lo.w, 16, 64);
  hi.x += __shfl_down(hi.x, 32, 64); hi.x += __shfl_down(hi.x, 16, 64);
  hi.y += __shfl_down(hi.y, 32, 64); hi.y += __shfl_down(hi.y, 16, 64);
  hi.z += __shfl_down(hi.z, 32, 64); hi.z += __shfl_down(hi.z, 16, 64);
  hi.w += __shfl_down(hi.w, 32, 64); hi.w += __shfl_down(hi.w, 16, 64);
  if (sub == 0) {
    float di = dinv[i];
    float4 b0 = ((const float4*)bias)[2 * c8];
    float4 b1 = ((const float4*)bias)[2 * c8 + 1];
    float4 o0, o1;
    o0.x = fmaxf(fmaf(di, lo.x, b0.x), 0.f);
    o0.y = fmaxf(fmaf(di, lo.y, b0.y), 0.f);
    o0.z = fmaxf(fmaf(di, lo.z, b0.z), 0.f);
    o0.w = fmaxf(fmaf(di, lo.w, b0.w), 0.f);
    o1.x = fmaxf(fmaf(di, hi.x, b1.x), 0.f);
    o1.y = fmaxf(fmaf(di, hi.y, b1.y), 0.f);
    o1.z = fmaxf(fmaf(di, hi.z, b1.z), 0.f);
    o1.w = fmaxf(fmaf(di, hi.w, b1.w), 0.f);
    ((float4*)out)[(size_t)i * 32 + 2 * c8] = o0;
    ((float4*)out)[(size_t)i * 32 + 2 * c8 + 1] = o1;
  }
}

// one wave per pair: sub0 loads A[p0] half4, sub1 loads B[p1] half4;
// combine via shfl_xor(32), dot with wh2, reduce.
__global__ __launch_bounds__(256) void k_pairs_h(
    const __half2* __restrict__ A, const __half2* __restrict__ B,
    const int* __restrict__ pairs, const float* __restrict__ bh1,
    const float* __restrict__ wh2, const float* __restrict__ bh2,
    float* __restrict__ out, int P) {
  int p = blockIdx.x * 4 + (threadIdx.x >> 6);
  int lane = threadIdx.x & 63;
  if (p >= P) return;
  int sub = lane >> 5, c4 = lane & 31;
  int p0 = pairs[2 * p], p1 = pairs[2 * p + 1];
  const uint2* T4 = sub ? (const uint2*)B : (const uint2*)A;
  int row = sub ? p1 : p0;
  float4 v = h4_to_f4(T4[(size_t)row * 32 + c4]);
  v.x += __shfl_xor(v.x, 32, 64);
  v.y += __shfl_xor(v.y, 32, 64);
  v.z += __shfl_xor(v.z, 32, 64);
  v.w += __shfl_xor(v.w, 32, 64);
  float4 bi = ((const float4*)bh1)[c4];
  float4 wv = ((const float4*)wh2)[c4];
  float s = fmaxf(v.x + bi.x, 0.f) * wv.x + fmaxf(v.y + bi.y, 0.f) * wv.y +
            fmaxf(v.z + bi.z, 0.f) * wv.z + fmaxf(v.w + bi.w, 0.f) * wv.w;
#pragma unroll
  for (int o = 16; o > 0; o >>= 1) s += __shfl_down(s, o, 64);
  if (lane == 0) out[p] = s + bh2[0];
}

extern "C" void kernel_launch(void* const* d_in, const int* in_sizes, int n_in,
                              void* d_out, int out_size, void* d_ws, size_t ws_size,
                              hipStream_t stream) {
  const float* x   = (const float*)d_in[0];
  const int* ei    = (const int*)d_in[1];
  const int* pairs = (const int*)d_in[2];
  const float* W1  = (const float*)d_in[3];
  const float* b1  = (const float*)d_in[4];
  const float* W2  = (const float*)d_in[5];
  const float* b2  = (const float*)d_in[6];
  const float* Wh1 = (const float*)d_in[7];
  const float* bh1 = (const float*)d_in[8];
  const float* Wh2 = (const float*)d_in[9];
  const float* bh2 = (const float*)d_in[10];
  (void)n_in; (void)out_size; (void)ws_size;

  int N = in_sizes[0] / 128;
  int E = in_sizes[1] / 2;
  int P = in_sizes[2] / 2;
  const int* src = ei;
  const int* dst = ei + E;
  int KB = (N + BSZ - 1) >> BSH;  // buckets (98 for N=50000)

  char* wsp = (char*)d_ws;
  size_t off = 0;
  auto alloc = [&](size_t bytes) -> void* {
    void* p = wsp + off;
    off += (bytes + 255) & ~(size_t)255;
    return p;
  };
  __half* g16 = (__half*)alloc((size_t)N * 128 * 2);  // messages; reused as A16
  float* h1   = (float*)alloc((size_t)N * 128 * 4);   // reused as B16 (fp16)
  float* h2   = (float*)alloc((size_t)N * 128 * 4);
  float* dinv = (float*)alloc((size_t)N * 4);
  int* rowptr = (int*)alloc((size_t)(N + 1) * 4);
  unsigned short* colarr = (unsigned short*)alloc((size_t)E * 2);
  int* tmp    = (int*)alloc((size_t)E * 4);           // packed bucketed edges
  short* fragH = (short*)alloc(4 * 2048 * 8 * 2);     // 128KB
  short* fragL = (short*)alloc(4 * 2048 * 8 * 2);     // 128KB
  int* gcnt  = (int*)alloc((size_t)(KB + 1) * 4);
  int* gcur  = (int*)alloc((size_t)(KB + 1) * 4);
  __half* A16 = g16;            // g16 dead by the time head runs
  __half* B16 = (__half*)h1;    // h1 dead after conv2 gemm
  // per-W frag bases (2048 slots * 8 shorts each)
  short* fH_W1 = fragH + 0 * 16384;  short* fL_W1 = fragL + 0 * 16384;
  short* fH_W2 = fragH + 1 * 16384;  short* fL_W2 = fragL + 1 * 16384;
  short* fH_Wa = fragH + 2 * 16384;  short* fL_Wa = fragL + 2 * 16384;
  short* fH_Wb = fragH + 3 * 16384;  short* fL_Wb = fragL + 3 * 16384;

  int GB = (N + 63) / 64;          // gemm: 64 rows per block
  int AB = (N + 3) / 4;            // agg: 4 rows per block

  // K1: weight frags + zero gcnt/gcur (block 32)
  k_prep_w<<<33, 256, 0, stream>>>(W1, W2, Wh1, fragH, fragL, gcnt, gcur, KB);
  // K2..K4: CSR build (hist -> multisplit -> bucket sort)
  k_hist<<<HB, 256, 0, stream>>>(dst, gcnt, E, KB);
  k_multisplit<<<(E + MSB - 1) / MSB, 256, 0, stream>>>(src, dst, gcnt, gcur,
                                                        tmp, E, KB);
  k_bucket_build<<<KB, 512, 0, stream>>>(tmp, gcnt, rowptr, dinv, colarr, N, KB, E);
  // K5..K10: convs + head (gemm1 AFTER bucket_build: it reads dinv)
  k_gemm_mfma<<<GB, 256, 0, stream>>>(x, fH_W1, fL_W1, dinv, g16, N);
  k_agg_h<<<AB, 256, 0, stream>>>((const __half2*)g16, dinv, rowptr, colarr, b1, h1, N);
  k_gemm_mfma<<<GB, 256, 0, stream>>>(h1, fH_W2, fL_W2, dinv, g16, N);
  k_agg_h<<<AB, 256, 0, stream>>>((const __half2*)g16, dinv, rowptr, colarr, b2, h2, N);
  k_gemm_dual<<<GB, 256, 0, stream>>>(h2, fH_Wa, fL_Wa, fH_Wb, fL_Wb, A16, B16, N);
  k_pairs_h<<<(P + 3) / 4, 256, 0, stream>>>((const __half2*)A16, (const __half2*)B16,
                                             pairs, bh1, Wh2, bh2, (float*)d_out, P);
}